// Round 1
// baseline (2703.380 us; speedup 1.0000x reference)
//
#include <hip/hip_runtime.h>
#include <math.h>

#define LN_EPS 1e-5f

typedef __attribute__((ext_vector_type(8))) short short8;   // 8 bf16 = 4 VGPRs
typedef __attribute__((ext_vector_type(4))) float floatx4;  // MFMA C/D

__device__ __forceinline__ unsigned short f32_to_bf16_rne(float v) {
    unsigned int u = __float_as_uint(v);
    return (unsigned short)((u + 0x7FFFu + ((u >> 16) & 1u)) >> 16);
}

// ---------------------------------------------------------------------------
// stats: sum(x_i), sum(x_i x_j) over rows of (P,3) -> 9 floats (atomicAdd)
// ---------------------------------------------------------------------------
__global__ __launch_bounds__(256) void stats_kernel(const float* __restrict__ x, int P,
                                                    float* __restrict__ stats) {
    int tid = blockIdx.x * blockDim.x + threadIdx.x;
    int stride = gridDim.x * blockDim.x;
    float s[9] = {0.f,0.f,0.f,0.f,0.f,0.f,0.f,0.f,0.f};
    for (int i = tid; i < P; i += stride) {
        float a = x[i*3+0], b = x[i*3+1], c = x[i*3+2];
        s[0]+=a; s[1]+=b; s[2]+=c;
        s[3]+=a*a; s[4]+=a*b; s[5]+=a*c;
        s[6]+=b*b; s[7]+=b*c; s[8]+=c*c;
    }
    #pragma unroll
    for (int j = 0; j < 9; j++) {
        float v = s[j];
        for (int off = 32; off > 0; off >>= 1) v += __shfl_down(v, off, 64);
        if ((threadIdx.x & 63) == 0) atomicAdd(&stats[j], v);
    }
}

// ---------------------------------------------------------------------------
// CSR grouping of points by node: count -> scan -> scatter (both encoders)
// ---------------------------------------------------------------------------
__global__ __launch_bounds__(256) void count_kernel(const int* __restrict__ bp,
                                                    const int* __restrict__ ba,
                                                    int Pp, int Pa,
                                                    int* __restrict__ cp,
                                                    int* __restrict__ ca) {
    int half = gridDim.x >> 1;
    bool isPos = blockIdx.x < (unsigned)half;
    const int* bidx = isPos ? bp : ba;
    int* cnt        = isPos ? cp : ca;
    int P           = isPos ? Pp : Pa;
    int b = isPos ? blockIdx.x : blockIdx.x - half;
    int stride = half * 256;
    for (int i = b*256 + threadIdx.x; i < P; i += stride)
        atomicAdd(&cnt[bidx[i]], 1);
}

// exclusive prefix scan of cnt -> base (block 0: pos, block 1: aff)
__global__ __launch_bounds__(256) void scan2_kernel(const int* __restrict__ cnt_pos,
                                                    const int* __restrict__ cnt_aff,
                                                    int* __restrict__ base_pos,
                                                    int* __restrict__ base_aff, int N) {
    const int* cnt = (blockIdx.x == 0) ? cnt_pos : cnt_aff;
    int* base      = (blockIdx.x == 0) ? base_pos : base_aff;
    __shared__ int wsum[4];
    __shared__ int carry;
    int tid = threadIdx.x, lane = tid & 63, wave = tid >> 6;
    if (tid == 0) carry = 0;
    __syncthreads();
    for (int t0 = 0; t0 < N; t0 += 256) {
        int i = t0 + tid;
        int v = (i < N) ? cnt[i] : 0;
        int s = v;
        #pragma unroll
        for (int off = 1; off < 64; off <<= 1) {
            int u = __shfl_up(s, off, 64);
            if (lane >= off) s += u;
        }
        if (lane == 63) wsum[wave] = s;
        __syncthreads();
        int woff = carry;
        for (int w = 0; w < wave; w++) woff += wsum[w];
        if (i < N) base[i] = woff + s - v;
        int total = wsum[0] + wsum[1] + wsum[2] + wsum[3];
        __syncthreads();
        if (tid == 0) carry += total;
        __syncthreads();
    }
}

// scatter: perm[base[n]++] = i. After this, base[n] == end offset of node n.
__global__ __launch_bounds__(256) void scatter_kernel(const int* __restrict__ bp,
                                                      const int* __restrict__ ba,
                                                      int Pp, int Pa,
                                                      int* __restrict__ base_pos,
                                                      int* __restrict__ base_aff,
                                                      int* __restrict__ perm_pos,
                                                      int* __restrict__ perm_aff) {
    int half = gridDim.x >> 1;
    bool isPos = blockIdx.x < (unsigned)half;
    const int* bidx = isPos ? bp : ba;
    int* base       = isPos ? base_pos : base_aff;
    int* perm       = isPos ? perm_pos : perm_aff;
    int P           = isPos ? Pp : Pa;
    int b = isPos ? blockIdx.x : blockIdx.x - half;
    int stride = half * 256;
    for (int i = b*256 + threadIdx.x; i < P; i += stride) {
        int n = bidx[i];
        int pos = atomicAdd(&base[n], 1);
        perm[pos] = i;
    }
}

// ---------------------------------------------------------------------------
// fold BN into W1/b1:  bn(x@W1+b1) = x@W1f + b1f   (exact: t linear in x)
// ---------------------------------------------------------------------------
__global__ void fold_bn_kernel(const float* __restrict__ stats,
                               const float* __restrict__ W1, const float* __restrict__ b1,
                               const float* __restrict__ g,  const float* __restrict__ b,
                               float Pinv,
                               float* __restrict__ W1f, float* __restrict__ b1f) {
    int c = threadIdx.x;
    float m0 = stats[0]*Pinv, m1 = stats[1]*Pinv, m2 = stats[2]*Pinv;
    float C00 = stats[3]*Pinv - m0*m0;
    float C01 = stats[4]*Pinv - m0*m1;
    float C02 = stats[5]*Pinv - m0*m2;
    float C11 = stats[6]*Pinv - m1*m1;
    float C12 = stats[7]*Pinv - m1*m2;
    float C22 = stats[8]*Pinv - m2*m2;
    float w0 = W1[c], w1 = W1[256+c], w2 = W1[512+c];
    float mean = m0*w0 + m1*w1 + m2*w2 + b1[c];
    float var  = C00*w0*w0 + C11*w1*w1 + C22*w2*w2
               + 2.f*(C01*w0*w1 + C02*w0*w2 + C12*w1*w2);
    float a = g[c] * rsqrtf(var + LN_EPS);
    W1f[c]     = w0*a;
    W1f[256+c] = w1*a;
    W1f[512+c] = w2*a;
    b1f[c] = (b1[c] - mean)*a + b[c];
}

// ---------------------------------------------------------------------------
// transpose + bf16-cast a 256x256 weight: Wt[n][k] = bf16(W[k][n])
// ---------------------------------------------------------------------------
__global__ void convert_w2_kernel(const float* __restrict__ W,
                                  unsigned short* __restrict__ Wt) {
    int n = blockIdx.x, k = threadIdx.x;
    Wt[n*256 + k] = f32_to_bf16_rne(W[k*256 + n]);
}

// ---------------------------------------------------------------------------
// node B: Bt[n][k], k<512: sem_comb[k][n]; 512..767: nf_W[256+j][n]; 768..1023: nf_W[512+j][n]
// ---------------------------------------------------------------------------
__global__ void convert_node_B(const float* __restrict__ sem_comb,
                               const float* __restrict__ nf_W,
                               unsigned short* __restrict__ Bt) {
    int n = blockIdx.x, t = threadIdx.x;
    Bt[n*1024 + t]       = f32_to_bf16_rne(sem_comb[t*256 + n]);
    Bt[n*1024 + 256 + t] = f32_to_bf16_rne(sem_comb[(256 + t)*256 + n]);
    Bt[n*1024 + 512 + t] = f32_to_bf16_rne(nf_W[(256 + t)*256 + n]);
    Bt[n*1024 + 768 + t] = f32_to_bf16_rne(nf_W[(512 + t)*256 + n]);
}

// ---------------------------------------------------------------------------
// edge B: Bt[n][k] (K padded to 320): k<256: param_comb; 256..279: anchor_comb;
// 280..288: pose_comb; 289..319: 0
// ---------------------------------------------------------------------------
__global__ void convert_edge_B(const float* __restrict__ param_comb,
                               const float* __restrict__ anchor_comb,
                               const float* __restrict__ pose_comb,
                               unsigned short* __restrict__ Bt) {
    int n = blockIdx.x, t = threadIdx.x;
    Bt[n*320 + t] = f32_to_bf16_rne(param_comb[t*256 + n]);
    if (t < 64) {
        float v = 0.f;
        if (t < 24)      v = anchor_comb[t*256 + n];
        else if (t < 33) v = pose_comb[(t - 24)*256 + n];
        Bt[n*320 + 256 + t] = f32_to_bf16_rne(v);
    }
}

// ---------------------------------------------------------------------------
// small C[r][c] = sum_j A[r*J+j] * B[j*256+c]   (grid = rows, block = 256)
// ---------------------------------------------------------------------------
__global__ void small_matmul_kernel(const float* __restrict__ A, const float* __restrict__ B,
                                    float* __restrict__ C, int J) {
    int r = blockIdx.x, c = threadIdx.x;
    const float* Ar = A + (size_t)r * J;
    float acc = 0.f;
    for (int j = 0; j < J; j++) acc += Ar[j] * B[j*256 + c];
    C[r*256 + c] = acc;
}

// ---------------------------------------------------------------------------
// constants: node_const = nf_b + sem_b@nf_W[0:256]
//            edge_const = ef_b + ep_b2@ef_W[256:512] + ea_b@ef_W[512:768] + epo_b@ef_W[768:1024]
// ---------------------------------------------------------------------------
__global__ void consts_kernel(const float* __restrict__ sem_b, const float* __restrict__ nf_W,
                              const float* __restrict__ nf_b,
                              const float* __restrict__ ep_b2, const float* __restrict__ ea_b,
                              const float* __restrict__ epo_b, const float* __restrict__ ef_W,
                              const float* __restrict__ ef_b,
                              float* __restrict__ node_const, float* __restrict__ edge_const) {
    int c = threadIdx.x;
    float nc = nf_b[c];
    for (int j = 0; j < 256; j++) nc += sem_b[j] * nf_W[j*256 + c];
    node_const[c] = nc;
    float ec = ef_b[c];
    for (int j = 0; j < 256; j++) ec += ep_b2[j] * ef_W[(256+j)*256 + c];
    for (int j = 0; j < 24;  j++) ec += ea_b[j]  * ef_W[(512+j)*256 + c];
    for (int j = 0; j < 9;   j++) ec += epo_b[j] * ef_W[(768+j)*256 + c];
    edge_const[c] = ec;
}

// ---------------------------------------------------------------------------
// point-cloud encoder v2: CSR-grouped points, segment-max in LDS.
// Block owns 32 consecutive nodes; its points are perm[s..e) (contiguous
// because nodes are consecutive). Tiles of 64 points through the validated
// layer1 -> bf16 LDS -> MFMA pipeline; max-accumulate into LDS segacc via
// ds-atomicMax (values >= 0 so uint compare == float compare). One coalesced
// atomic-free write of 32x256 at the end. No global atomics, no memset need.
// LDS: u 33.8 KB + segacc 33.3 KB + small  -> 2 blocks/CU.
// ---------------------------------------------------------------------------
#define USTRIDE 264
#define SEG_STRIDE 260

__global__ __launch_bounds__(256) void pce_seg_kernel(
    const float* __restrict__ x, const int* __restrict__ bidx,
    const int* __restrict__ perm, const int* __restrict__ base_end,
    const float* __restrict__ W1f, const float* __restrict__ b1f,
    const unsigned short* __restrict__ Wt, const float* __restrict__ b2,
    float* __restrict__ seg, int N)
{
    __shared__ unsigned short u[64 * USTRIDE];
    __shared__ unsigned int segacc[32 * SEG_STRIDE];
    __shared__ float xs[64 * 3];
    __shared__ int ndl[64];
    __shared__ int prm[64];

    int tid = threadIdx.x;
    int n0 = blockIdx.x * 32;
    int nlast = min(n0 + 32, N) - 1;
    int s = (n0 == 0) ? 0 : base_end[n0 - 1];
    int e = base_end[nlast];

    for (int i = tid; i < 32 * SEG_STRIDE; i += 256) segacc[i] = 0u;

    int wave  = tid >> 6;
    int lane  = tid & 63;
    int lrow  = lane & 15;
    int lquad = lane >> 4;
    int nbase = wave * 64;

    // loop-invariant per-thread params
    int c = tid;
    float w0 = W1f[c], w1 = W1f[256+c], w2 = W1f[512+c], bb = b1f[c];
    float bias[4];
    #pragma unroll
    for (int ni = 0; ni < 4; ni++) bias[ni] = b2[nbase + ni*16 + lrow];

    for (int ts = s; ts < e; ts += 64) {
        int np = min(64, e - ts);
        __syncthreads();   // prev iteration done with xs/ndl/u (and segacc init)
        if (tid < 64) {
            int pi = (tid < np) ? perm[ts + tid] : -1;
            prm[tid] = pi;
            ndl[tid] = (pi >= 0) ? (bidx[pi] - n0) : -1;
        }
        __syncthreads();
        if (tid < 192) {
            int p = tid / 3;
            int pi = prm[p];
            xs[tid] = (pi >= 0) ? x[(size_t)pi*3 + (tid - p*3)] : 0.f;
        }
        __syncthreads();

        // layer 1 (BN folded): each thread owns one output col
        for (int p = 0; p < 64; p++) {
            float v = 0.f;
            if (p < np) v = fmaxf(xs[p*3]*w0 + xs[p*3+1]*w1 + xs[p*3+2]*w2 + bb, 0.f);
            u[p*USTRIDE + c] = f32_to_bf16_rne(v);
        }
        __syncthreads();

        floatx4 acc[4][4];
        #pragma unroll
        for (int mi = 0; mi < 4; mi++)
            #pragma unroll
            for (int ni = 0; ni < 4; ni++)
                acc[mi][ni] = (floatx4){0.f, 0.f, 0.f, 0.f};

        #pragma unroll
        for (int kc = 0; kc < 8; kc++) {
            int k0 = kc*32 + lquad*8;
            short8 a[4], b[4];
            #pragma unroll
            for (int mi = 0; mi < 4; mi++)
                a[mi] = *(const short8*)&u[(mi*16 + lrow)*USTRIDE + k0];
            #pragma unroll
            for (int ni = 0; ni < 4; ni++)
                b[ni] = *(const short8*)&Wt[(size_t)(nbase + ni*16 + lrow)*256 + k0];
            #pragma unroll
            for (int mi = 0; mi < 4; mi++)
                #pragma unroll
                for (int ni = 0; ni < 4; ni++)
                    acc[mi][ni] = __builtin_amdgcn_mfma_f32_16x16x32_bf16(
                                      a[mi], b[ni], acc[mi][ni], 0, 0, 0);
        }

        // epilogue: relu(acc+bias) -> LDS segment max. Rows are sorted by
        // node, so dedupe runs within each lane's 4 consecutive rows.
        #pragma unroll
        for (int ni = 0; ni < 4; ni++) {
            int col = nbase + ni*16 + lrow;
            #pragma unroll
            for (int mi = 0; mi < 4; mi++) {
                int cur = -1; float best = 0.f;
                #pragma unroll
                for (int r = 0; r < 4; r++) {
                    int m = mi*16 + lquad*4 + r;
                    int nd = ndl[m];
                    float y = fmaxf(acc[mi][ni][r] + bias[ni], 0.f);
                    if (nd != cur) {
                        if (cur >= 0)
                            atomicMax(&segacc[cur*SEG_STRIDE + col],
                                      __float_as_uint(best));
                        cur = nd; best = y;
                    } else {
                        best = fmaxf(best, y);
                    }
                }
                if (cur >= 0)
                    atomicMax(&segacc[cur*SEG_STRIDE + col], __float_as_uint(best));
            }
        }
    }

    __syncthreads();
    for (int t = 0; t < 32; t++) {
        int n = n0 + t;
        if (n <= nlast)
            seg[(size_t)n*256 + tid] = __uint_as_float(segacc[t*SEG_STRIDE + tid]);
    }
}

// ---------------------------------------------------------------------------
// LN reduce helpers: rows of 256 fp32 in LDS (given stride), write mean/rstd
// ---------------------------------------------------------------------------
__device__ __forceinline__ void ln_reduce_rows16(const float* __restrict__ rows, int stride,
                                                 float (*mr)[2], int tid) {
    int wave = tid >> 6, lane = tid & 63;
    for (int t = 0; t < 16; t++) {
        int n = wave*16 + t;
        const float* r = rows + n*stride;
        float v0 = r[lane], v1 = r[64+lane], v2 = r[128+lane], v3 = r[192+lane];
        float s = v0+v1+v2+v3;
        float q = v0*v0+v1*v1+v2*v2+v3*v3;
        for (int off = 32; off > 0; off >>= 1) {
            s += __shfl_down(s, off, 64);
            q += __shfl_down(q, off, 64);
        }
        if (lane == 0) {
            float mean = s * (1.f/256.f);
            mr[n][0] = mean;
            mr[n][1] = rsqrtf(q * (1.f/256.f) - mean*mean + LN_EPS);
        }
    }
}

__device__ __forceinline__ void ln_reduce_rows2(const float* __restrict__ rows, int stride,
                                                float (*mr)[2], int tid) {
    int wave = tid >> 6, lane = tid & 63;
    #pragma unroll
    for (int t = 0; t < 2; t++) {
        int n = wave*2 + t;
        const float* r = rows + n*stride;
        float v0 = r[lane], v1 = r[64+lane], v2 = r[128+lane], v3 = r[192+lane];
        float s = v0+v1+v2+v3;
        float q = v0*v0+v1*v1+v2*v2+v3*v3;
        for (int off = 32; off > 0; off >>= 1) {
            s += __shfl_down(s, off, 64);
            q += __shfl_down(q, off, 64);
        }
        if (lane == 0) {
            float mean = s * (1.f/256.f);
            mr[n][0] = mean;
            mr[n][1] = rsqrtf(q * (1.f/256.f) - mean*mean + LN_EPS);
        }
    }
}

// ---------------------------------------------------------------------------
// node MFMA: 64 nodes/block. A = [x_sem | h_pos | h_aff] bf16, K=1024 in 4
// chunks of 256 staged through LDS (stride 264). B = BtN[n][k] bf16 (L2).
// Epilogue: +node_const -> LDS fp32 (stride 260) -> LN -> relu -> out.
// LDS: union(A-chunk 33 KB, pre 66.5 KB) = 66.5 KB -> 2 blocks/CU.
// ---------------------------------------------------------------------------
#define NA_STRIDE 264
#define NP_STRIDE 260

__global__ __launch_bounds__(256) void node_mfma_kernel(
    const float* __restrict__ x_sem, const float* __restrict__ h_pos,
    const float* __restrict__ h_aff,
    const unsigned short* __restrict__ BtN,
    const float* __restrict__ node_const,
    const float* __restrict__ ln_g, const float* __restrict__ ln_b,
    float* __restrict__ out, int N)
{
    __shared__ __align__(16) float smem[64 * NP_STRIDE];  // union: A chunk / pre
    unsigned short* As = (unsigned short*)smem;
    float* pre = smem;
    __shared__ float mr[64][2];

    int tid = threadIdx.x;
    int base = blockIdx.x * 64;
    int nn = min(64, N - base);

    int wave  = tid >> 6;
    int lane  = tid & 63;
    int lrow  = lane & 15;
    int lquad = lane >> 4;
    int nbase = wave * 64;

    floatx4 acc[4][4];
    #pragma unroll
    for (int mi = 0; mi < 4; mi++)
        #pragma unroll
        for (int ni = 0; ni < 4; ni++)
            acc[mi][ni] = (floatx4){0.f, 0.f, 0.f, 0.f};

    #pragma unroll
    for (int chunk = 0; chunk < 4; chunk++) {
        const float* src; int sstride;
        if (chunk == 0)      { src = x_sem + (size_t)base*512;       sstride = 512; }
        else if (chunk == 1) { src = x_sem + (size_t)base*512 + 256; sstride = 512; }
        else if (chunk == 2) { src = h_pos + (size_t)base*256;       sstride = 256; }
        else                 { src = h_aff + (size_t)base*256;       sstride = 256; }

        for (int i = tid; i < 64*64; i += 256) {
            int row = i >> 6, c4 = (i & 63) * 4;
            float4 v = {0.f, 0.f, 0.f, 0.f};
            if (row < nn) v = *(const float4*)&src[(size_t)row*sstride + c4];
            ushort4 h;
            h.x = f32_to_bf16_rne(v.x); h.y = f32_to_bf16_rne(v.y);
            h.z = f32_to_bf16_rne(v.z); h.w = f32_to_bf16_rne(v.w);
            *(ushort4*)&As[row*NA_STRIDE + c4] = h;
        }
        __syncthreads();

        #pragma unroll
        for (int kc = 0; kc < 8; kc++) {
            int k0 = kc*32 + lquad*8;
            short8 a[4], b[4];
            #pragma unroll
            for (int mi = 0; mi < 4; mi++)
                a[mi] = *(const short8*)&As[(mi*16 + lrow)*NA_STRIDE + k0];
            #pragma unroll
            for (int ni = 0; ni < 4; ni++)
                b[ni] = *(const short8*)&BtN[(size_t)(nbase + ni*16 + lrow)*1024
                                             + chunk*256 + k0];
            #pragma unroll
            for (int mi = 0; mi < 4; mi++)
                #pragma unroll
                for (int ni = 0; ni < 4; ni++)
                    acc[mi][ni] = __builtin_amdgcn_mfma_f32_16x16x32_bf16(
                                      a[mi], b[ni], acc[mi][ni], 0, 0, 0);
        }
        __syncthreads();   // before next chunk (or pre-write) reuses smem
    }

    // epilogue: pre = acc + node_const
    #pragma unroll
    for (int ni = 0; ni < 4; ni++) {
        int col = nbase + ni*16 + lrow;
        float cst = node_const[col];
        #pragma unroll
        for (int mi = 0; mi < 4; mi++)
            #pragma unroll
            for (int r = 0; r < 4; r++) {
                int m = mi*16 + lquad*4 + r;
                pre[m*NP_STRIDE + col] = acc[mi][ni][r] + cst;
            }
    }
    __syncthreads();
    ln_reduce_rows16(pre, NP_STRIDE, mr, tid);
    __syncthreads();

    float gc = ln_g[tid], bc = ln_b[tid];
    for (int m = 0; m < 64; m++) {
        if (m < nn) {
            float y = (pre[m*NP_STRIDE + tid] - mr[m][0]) * mr[m][1] * gc + bc;
            out[(size_t)(base + m)*256 + tid] = fmaxf(y, 0.f);
        }
    }
}

// ---------------------------------------------------------------------------
// edge MFMA: 64 edges/block. h1 = relu(LN(v@ep_W1+b1)) computed in 8 groups
// of 8 rows into A bf16 [64 x 320] (cols 256..288 = anchor|pose, 289.. = 0).
// MFMA K=320 vs BtE. Epilogue: + type_proj[ty] + edge_const -> LN -> relu.
// LDS: union(A 42 KB / pre 66.5 KB, h1tmp at +48K) + va/ty/mr ~ 69 KB.
// ---------------------------------------------------------------------------
#define EA_STRIDE 328
#define EP_STRIDE 260

__global__ __launch_bounds__(256) void edge_mfma_kernel(
    const int* __restrict__ etype, const float* __restrict__ eparam,
    const float* __restrict__ eanchor, const float* __restrict__ epose,
    const float* __restrict__ ep_W1, const float* __restrict__ ep_b1,
    const float* __restrict__ ep_ln_g, const float* __restrict__ ep_ln_b,
    const unsigned short* __restrict__ BtE,
    const float* __restrict__ type_proj, const float* __restrict__ edge_const,
    const float* __restrict__ ln_g, const float* __restrict__ ln_b,
    float* __restrict__ out, int E)
{
    __shared__ __align__(16) float smem[64 * EP_STRIDE];   // union
    unsigned short* As = (unsigned short*)smem;            // 64*328*2 = 41984 B
    float* pre = smem;                                     // 64*260*4 = 66560 B
    float* h1tmp = smem + 12288;                           // 49152 B offset; 8*260*4 = 8320 B
    __shared__ float va[64][5];
    __shared__ int   ty[64];
    __shared__ float mr[64][2];
    __shared__ float mr8[8][2];

    int tid = threadIdx.x;
    int base = blockIdx.x * 64;
    int ne = min(64, E - base);

    // zero A tile (covers the pad columns); compute va/ty
    for (int i = tid; i < 64*EA_STRIDE/4; i += 256)
        ((ushort4*)As)[i] = (ushort4){0, 0, 0, 0};
    if (tid < 64) {
        int e = tid;
        if (e < ne) {
            float d  = eparam[(size_t)(base+e)*3 + 0];
            float th = eparam[(size_t)(base+e)*3 + 1];
            float ph = eparam[(size_t)(base+e)*3 + 2];
            va[e][0] = fminf(fmaxf(d*10.f, -5.f), 5.f);
            va[e][1] = __sinf(th); va[e][2] = __cosf(th);
            va[e][3] = __sinf(ph); va[e][4] = __cosf(ph);
            ty[e] = etype[base+e];
        } else {
            va[e][0]=va[e][1]=va[e][2]=va[e][3]=va[e][4]=0.f; ty[e]=0;
        }
    }
    __syncthreads();

    // anchor/pose into A cols 256..288
    for (int i = tid; i < 64*24; i += 256) {
        float v = (i < ne*24) ? eanchor[(size_t)base*24 + i] : 0.f;
        As[(i/24)*EA_STRIDE + 256 + (i % 24)] = f32_to_bf16_rne(v);
    }
    for (int i = tid; i < 64*9; i += 256) {
        float v = (i < ne*9) ? epose[(size_t)base*9 + i] : 0.f;
        As[(i/9)*EA_STRIDE + 280 + (i % 9)] = f32_to_bf16_rne(v);
    }

    // h1 rows in 8 groups of 8
    int c = tid;
    float w0=ep_W1[c], w1=ep_W1[256+c], w2=ep_W1[512+c], w3=ep_W1[768+c], w4=ep_W1[1024+c];
    float bb = ep_b1[c];
    float gc1 = ep_ln_g[c], bc1 = ep_ln_b[c];
    for (int g = 0; g < 8; g++) {
        float t[8];
        #pragma unroll
        for (int e = 0; e < 8; e++) {
            int ge = g*8 + e;
            t[e] = va[ge][0]*w0 + va[ge][1]*w1 + va[ge][2]*w2 + va[ge][3]*w3
                 + va[ge][4]*w4 + bb;
            h1tmp[e*EP_STRIDE + c] = t[e];
        }
        __syncthreads();
        ln_reduce_rows2(h1tmp, EP_STRIDE, mr8, tid);
        __syncthreads();
        #pragma unroll
        for (int e = 0; e < 8; e++) {
            float y = fmaxf((t[e] - mr8[e][0]) * mr8[e][1] * gc1 + bc1, 0.f);
            As[(g*8 + e)*EA_STRIDE + c] = f32_to_bf16_rne(y);
        }
        __syncthreads();
    }

    int wave  = tid >> 6;
    int lane  = tid & 63;
    int lrow  = lane & 15;
    int lquad = lane >> 4;
    int nbase = wave * 64;

    floatx4 acc[4][4];
    #pragma unroll
    for (int mi = 0; mi < 4; mi++)
        #pragma unroll
        for (int ni = 0; ni < 4; ni++)
            acc[mi][ni] = (floatx4){0.f, 0.f, 0.f, 0.f};

    #pragma unroll
    for (int kc = 0; kc < 10; kc++) {
        int k0 = kc*32 + lquad*8;
        short8 a[4], b[4];
        #pragma unroll
        for (int mi = 0; mi < 4; mi++)
            a[mi] = *(const short8*)&As[(mi*16 + lrow)*EA_STRIDE + k0];
        #pragma unroll
        for (int ni = 0; ni < 4; ni++)
            b[ni] = *(const short8*)&BtE[(size_t)(nbase + ni*16 + lrow)*320 + k0];
        #pragma unroll
        for (int mi = 0; mi < 4; mi++)
            #pragma unroll
            for (int ni = 0; ni < 4; ni++)
                acc[mi][ni] = __builtin_amdgcn_mfma_f32_16x16x32_bf16(
                                  a[mi], b[ni], acc[mi][ni], 0, 0, 0);
    }
    __syncthreads();   // done reading As; smem becomes pre

    #pragma unroll
    for (int ni = 0; ni < 4; ni++) {
        int col = nbase + ni*16 + lrow;
        float cst = edge_const[col];
        #pragma unroll
        for (int mi = 0; mi < 4; mi++)
            #pragma unroll
            for (int r = 0; r < 4; r++) {
                int m = mi*16 + lquad*4 + r;
                pre[m*EP_STRIDE + col] = acc[mi][ni][r] + cst
                                       + type_proj[ty[m]*256 + col];
            }
    }
    __syncthreads();
    ln_reduce_rows16(pre, EP_STRIDE, mr, tid);
    __syncthreads();

    float gc = ln_g[tid], bc = ln_b[tid];
    for (int m = 0; m < 64; m++) {
        if (m < ne) {
            float y = (pre[m*EP_STRIDE + tid] - mr[m][0]) * mr[m][1] * gc + bc;
            out[(size_t)(base + m)*256 + tid] = fmaxf(y, 0.f);
        }
    }
}

// ---------------------------------------------------------------------------
extern "C" void kernel_launch(void* const* d_in, const int* in_sizes, int n_in,
                              void* d_out, int out_size, void* d_ws, size_t ws_size,
                              hipStream_t stream)
{
    const float* x_sem     = (const float*)d_in[0];
    const float* x_pos     = (const float*)d_in[1];
    const int*   pos_bidx  = (const int*)  d_in[2];
    const float* x_aff     = (const float*)d_in[3];
    const int*   aff_bidx  = (const int*)  d_in[4];
    const int*   edge_type = (const int*)  d_in[5];
    const float* edge_param  = (const float*)d_in[6];
    const float* edge_anchor = (const float*)d_in[7];
    const float* edge_pose   = (const float*)d_in[8];
    const float* sem_W  = (const float*)d_in[10];
    const float* sem_b  = (const float*)d_in[11];
    const float* pos_W1 = (const float*)d_in[12];
    const float* pos_b1 = (const float*)d_in[13];
    const float* pos_bn_g = (const float*)d_in[14];
    const float* pos_bn_b = (const float*)d_in[15];
    const float* pos_W2 = (const float*)d_in[16];
    const float* pos_b2 = (const float*)d_in[17];
    const float* aff_W1 = (const float*)d_in[18];
    const float* aff_b1 = (const float*)d_in[19];
    const float* aff_bn_g = (const float*)d_in[20];
    const float* aff_bn_b = (const float*)d_in[21];
    const float* aff_W2 = (const float*)d_in[22];
    const float* aff_b2 = (const float*)d_in[23];
    const float* nf_W   = (const float*)d_in[24];
    const float* nf_b   = (const float*)d_in[25];
    const float* nf_ln_g = (const float*)d_in[26];
    const float* nf_ln_b = (const float*)d_in[27];
    const float* et_emb = (const float*)d_in[28];
    const float* ep_W1  = (const float*)d_in[29];
    const float* ep_b1  = (const float*)d_in[30];
    const float* ep_ln_g = (const float*)d_in[31];
    const float* ep_ln_b = (const float*)d_in[32];
    const float* ep_W2  = (const float*)d_in[33];
    const float* ep_b2  = (const float*)d_in[34];
    const float* ea_W   = (const float*)d_in[35];
    const float* ea_b   = (const float*)d_in[36];
    const float* epo_W  = (const float*)d_in[37];
    const float* epo_b  = (const float*)d_in[38];
    const float* ef_W   = (const float*)d_in[39];
    const float* ef_b   = (const float*)d_in[40];
    const float* ef_ln_g = (const float*)d_in[41];
    const float* ef_ln_b = (const float*)d_in[42];

    int N  = in_sizes[0] / 512;
    int Pp = in_sizes[1] / 3;
    int Pa = in_sizes[3] / 3;
    int E  = in_sizes[5];

    float* ws = (float*)d_ws;
    float* h_pos      = ws;                              // N*256
    float* h_aff      = h_pos + (size_t)N*256;           // N*256
    float* stats_pos  = h_aff + (size_t)N*256;           // 16
    float* stats_aff  = stats_pos + 16;                  // 16
    int*   cnt_pos    = (int*)(stats_aff + 16);          // N (memset 0)
    int*   cnt_aff    = cnt_pos + N;                     // N (memset 0)
    int*   base_pos   = cnt_aff + N;                     // N
    int*   base_aff   = base_pos + N;                    // N
    int*   perm_pos   = base_aff + N;                    // Pp
    int*   perm_aff   = perm_pos + Pp;                   // Pa
    float* pos_W1f    = (float*)(perm_aff + Pa);         // 768
    float* pos_b1f    = pos_W1f + 768;                   // 256
    float* aff_W1f    = pos_b1f + 256;                   // 768
    float* aff_b1f    = aff_W1f + 768;                   // 256
    float* sem_comb   = aff_b1f + 256;                   // 512*256
    float* param_comb = sem_comb + 512*256;              // 256*256
    float* anchor_comb= param_comb + 256*256;            // 24*256
    float* pose_comb  = anchor_comb + 24*256;            // 9*256
    float* type_proj  = pose_comb + 9*256;               // 7*256
    float* node_const = type_proj + 7*256;               // 256
    float* edge_const = node_const + 256;                // 256
    unsigned short* pos_Wt = (unsigned short*)(edge_const + 256);  // 256*256 bf16
    unsigned short* aff_Wt = pos_Wt + 256*256;                     // 256*256 bf16
    unsigned short* BtN    = aff_Wt + 256*256;                     // 256*1024 bf16
    unsigned short* BtE    = BtN + 256*1024;                       // 256*320 bf16

    // zero stats + CSR counters only (h_pos/h_aff are now fully written,
    // every node exactly once -> no 102 MB memset needed)
    hipMemsetAsync(stats_pos, 0, (32 + 2*(size_t)N) * sizeof(float), stream);

    stats_kernel<<<512, 256, 0, stream>>>(x_pos, Pp, stats_pos);
    stats_kernel<<<512, 256, 0, stream>>>(x_aff, Pa, stats_aff);
    count_kernel<<<1024, 256, 0, stream>>>(pos_bidx, aff_bidx, Pp, Pa, cnt_pos, cnt_aff);
    scan2_kernel<<<2, 256, 0, stream>>>(cnt_pos, cnt_aff, base_pos, base_aff, N);
    scatter_kernel<<<1024, 256, 0, stream>>>(pos_bidx, aff_bidx, Pp, Pa,
                                             base_pos, base_aff, perm_pos, perm_aff);

    fold_bn_kernel<<<1, 256, 0, stream>>>(stats_pos, pos_W1, pos_b1, pos_bn_g, pos_bn_b,
                                          1.f/(float)Pp, pos_W1f, pos_b1f);
    fold_bn_kernel<<<1, 256, 0, stream>>>(stats_aff, aff_W1, aff_b1, aff_bn_g, aff_bn_b,
                                          1.f/(float)Pa, aff_W1f, aff_b1f);
    convert_w2_kernel<<<256, 256, 0, stream>>>(pos_W2, pos_Wt);
    convert_w2_kernel<<<256, 256, 0, stream>>>(aff_W2, aff_Wt);

    small_matmul_kernel<<<512, 256, 0, stream>>>(sem_W,  nf_W,            sem_comb,   256);
    small_matmul_kernel<<<256, 256, 0, stream>>>(ep_W2,  ef_W + 256*256,  param_comb, 256);
    small_matmul_kernel<<<24,  256, 0, stream>>>(ea_W,   ef_W + 512*256,  anchor_comb,256);
    small_matmul_kernel<<<9,   256, 0, stream>>>(epo_W,  ef_W + 768*256,  pose_comb,  256);
    small_matmul_kernel<<<7,   256, 0, stream>>>(et_emb, ef_W,            type_proj,  256);
    consts_kernel<<<1, 256, 0, stream>>>(sem_b, nf_W, nf_b, ep_b2, ea_b, epo_b, ef_W, ef_b,
                                         node_const, edge_const);
    convert_node_B<<<256, 256, 0, stream>>>(sem_comb, nf_W, BtN);
    convert_edge_B<<<256, 256, 0, stream>>>(param_comb, anchor_comb, pose_comb, BtE);

    // after scatter, base_* hold END offsets per node
    pce_seg_kernel<<<(N + 31)/32, 256, 0, stream>>>(x_pos, pos_bidx, perm_pos, base_pos,
                                                    pos_W1f, pos_b1f, pos_Wt, pos_b2,
                                                    h_pos, N);
    pce_seg_kernel<<<(N + 31)/32, 256, 0, stream>>>(x_aff, aff_bidx, perm_aff, base_aff,
                                                    aff_W1f, aff_b1f, aff_Wt, aff_b2,
                                                    h_aff, N);

    node_mfma_kernel<<<(N + 63)/64, 256, 0, stream>>>(x_sem, h_pos, h_aff, BtN, node_const,
                                                      nf_ln_g, nf_ln_b,
                                                      (float*)d_out, N);
    edge_mfma_kernel<<<(E + 63)/64, 256, 0, stream>>>(edge_type, edge_param, edge_anchor,
                                                      edge_pose, ep_W1, ep_b1,
                                                      ep_ln_g, ep_ln_b, BtE,
                                                      type_proj, edge_const,
                                                      ef_ln_g, ef_ln_b,
                                                      (float*)d_out + (size_t)N*256, E);
}

// Round 3
// 2148.061 us; speedup vs baseline: 1.2585x; 1.2585x over previous
//
#include <hip/hip_runtime.h>
#include <math.h>

#define LN_EPS 1e-5f

typedef __attribute__((ext_vector_type(8))) short short8;   // 8 bf16 = 4 VGPRs
typedef __attribute__((ext_vector_type(4))) float floatx4;  // MFMA C/D
typedef __attribute__((ext_vector_type(4))) int   intx4;

__device__ __forceinline__ unsigned short f32_to_bf16_rne(float v) {
    unsigned int u = __float_as_uint(v);
    return (unsigned short)((u + 0x7FFFu + ((u >> 16) & 1u)) >> 16);
}

// pack two fp32 -> one dword of 2 bf16 (RNE), lo in bits 0..15
__device__ __forceinline__ int pack2_bf16(float lo, float hi) {
    unsigned int r = ((unsigned int)f32_to_bf16_rne(hi) << 16)
                   |  (unsigned int)f32_to_bf16_rne(lo);
    return (int)r;
}

// ---------------------------------------------------------------------------
// stats (merged pos+aff): sum(x_i), sum(x_i x_j) over (P,3) -> 9 floats each
// ---------------------------------------------------------------------------
__global__ __launch_bounds__(256) void stats_kernel(const float* __restrict__ xp, int Pp,
                                                    const float* __restrict__ xa, int Pa,
                                                    float* __restrict__ stats) {
    int half = gridDim.x >> 1;
    bool aff = (int)blockIdx.x >= half;
    const float* x = aff ? xa : xp;
    int P = aff ? Pa : Pp;
    float* st = stats + (aff ? 16 : 0);
    int b = aff ? blockIdx.x - half : blockIdx.x;
    int tid = b * 256 + threadIdx.x;
    int stride = half * 256;
    float s[9] = {0.f,0.f,0.f,0.f,0.f,0.f,0.f,0.f,0.f};
    for (int i = tid; i < P; i += stride) {
        float a = x[i*3+0], bb = x[i*3+1], c = x[i*3+2];
        s[0]+=a; s[1]+=bb; s[2]+=c;
        s[3]+=a*a; s[4]+=a*bb; s[5]+=a*c;
        s[6]+=bb*bb; s[7]+=bb*c; s[8]+=c*c;
    }
    #pragma unroll
    for (int j = 0; j < 9; j++) {
        float v = s[j];
        for (int off = 32; off > 0; off >>= 1) v += __shfl_down(v, off, 64);
        if ((threadIdx.x & 63) == 0) atomicAdd(&st[j], v);
    }
}

// ---------------------------------------------------------------------------
// CSR grouping: count -> scan -> scatter (scatter also gathers x into sorted
// order as padded float4 + node id, so pce needs NO dependent gathers)
// ---------------------------------------------------------------------------
__global__ __launch_bounds__(256) void count_kernel(const int* __restrict__ bp,
                                                    const int* __restrict__ ba,
                                                    int Pp, int Pa,
                                                    int* __restrict__ cp,
                                                    int* __restrict__ ca) {
    int half = gridDim.x >> 1;
    bool isAff = (int)blockIdx.x >= half;
    const int* bidx = isAff ? ba : bp;
    int* cnt        = isAff ? ca : cp;
    int P           = isAff ? Pa : Pp;
    int b = isAff ? blockIdx.x - half : blockIdx.x;
    int stride = half * 256;
    for (int i = b*256 + threadIdx.x; i < P; i += stride)
        atomicAdd(&cnt[bidx[i]], 1);
}

// exclusive scan, 1024 threads, int4 per thread (cnt padded to N2 with zeros)
__global__ __launch_bounds__(1024) void scan2_kernel(const int* __restrict__ cnt_pos,
                                                     const int* __restrict__ cnt_aff,
                                                     int* __restrict__ base_pos,
                                                     int* __restrict__ base_aff, int N) {
    const int* cnt = blockIdx.x ? cnt_aff : cnt_pos;
    int* base      = blockIdx.x ? base_aff : base_pos;
    __shared__ int wsum[16];
    __shared__ int carry;
    int tid = threadIdx.x, lane = tid & 63, wave = tid >> 6;
    if (tid == 0) carry = 0;
    __syncthreads();
    for (int t0 = 0; t0 < N; t0 += 4096) {
        int i4 = t0 + tid * 4;
        int4 v = *(const int4*)&cnt[i4];          // padded -> always in-bounds
        int tt = v.x + v.y + v.z + v.w;
        int s = tt;
        #pragma unroll
        for (int off = 1; off < 64; off <<= 1) {
            int u = __shfl_up(s, off, 64);
            if (lane >= off) s += u;
        }
        __syncthreads();                          // (A) prev chunk fully done
        if (lane == 63) wsum[wave] = s;
        __syncthreads();                          // (B)
        int c0 = carry;
        int woff = c0, tot = 0;
        #pragma unroll
        for (int w = 0; w < 16; w++) { int z = wsum[w]; tot += z; if (w < wave) woff += z; }
        int excl = woff + s - tt;
        if (i4     < N) base[i4]     = excl;
        if (i4 + 1 < N) base[i4 + 1] = excl + v.x;
        if (i4 + 2 < N) base[i4 + 2] = excl + v.x + v.y;
        if (i4 + 3 < N) base[i4 + 3] = excl + v.x + v.y + v.z;
        __syncthreads();                          // (C) all read carry/wsum
        if (tid == 0) carry = c0 + tot;
    }
}

// scatter: pos = base[n]++; xsort[pos] = {x,y,z,0}; ndsort[pos] = n.
// After this, base[n] == end offset of node n.
__global__ __launch_bounds__(256) void scatter_kernel(
    const float* __restrict__ xp, const int* __restrict__ bp, int Pp,
    const float* __restrict__ xa, const int* __restrict__ ba, int Pa,
    int* __restrict__ base_pos, int* __restrict__ base_aff,
    float4* __restrict__ xs_pos, int* __restrict__ nd_pos,
    float4* __restrict__ xs_aff, int* __restrict__ nd_aff) {
    int half = gridDim.x >> 1;
    bool isAff = (int)blockIdx.x >= half;
    const float* x  = isAff ? xa : xp;
    const int* bidx = isAff ? ba : bp;
    int P           = isAff ? Pa : Pp;
    int* base       = isAff ? base_aff : base_pos;
    float4* xs      = isAff ? xs_aff : xs_pos;
    int* nd         = isAff ? nd_aff : nd_pos;
    int b = isAff ? blockIdx.x - half : blockIdx.x;
    int stride = half * 256;
    for (int i = b*256 + threadIdx.x; i < P; i += stride) {
        int n = bidx[i];
        int pos = atomicAdd(&base[n], 1);
        float4 v;
        v.x = x[i*3+0]; v.y = x[i*3+1]; v.z = x[i*3+2]; v.w = 0.f;
        xs[pos] = v;
        nd[pos] = n;
    }
}

// ---------------------------------------------------------------------------
// fold BN into W1/b1 (merged pos/aff): bn(x@W1+b1) = x@W1f + b1f
// ---------------------------------------------------------------------------
__global__ void fold_bn_kernel(const float* __restrict__ stats_all,
                               const float* __restrict__ W1p, const float* __restrict__ b1p,
                               const float* __restrict__ gp,  const float* __restrict__ bgp,
                               const float* __restrict__ W1a, const float* __restrict__ b1a,
                               const float* __restrict__ ga,  const float* __restrict__ bga,
                               float Pinv_p, float Pinv_a,
                               float* __restrict__ W1f_all, float* __restrict__ b1f_all) {
    int sel = blockIdx.x;
    const float* stats = stats_all + sel*16;
    const float* W1 = sel ? W1a : W1p;
    const float* b1 = sel ? b1a : b1p;
    const float* g  = sel ? ga  : gp;
    const float* b  = sel ? bga : bgp;
    float Pinv = sel ? Pinv_a : Pinv_p;
    float* W1f = W1f_all + sel*768;
    float* b1f = b1f_all + sel*256;
    int c = threadIdx.x;
    float m0 = stats[0]*Pinv, m1 = stats[1]*Pinv, m2 = stats[2]*Pinv;
    float C00 = stats[3]*Pinv - m0*m0;
    float C01 = stats[4]*Pinv - m0*m1;
    float C02 = stats[5]*Pinv - m0*m2;
    float C11 = stats[6]*Pinv - m1*m1;
    float C12 = stats[7]*Pinv - m1*m2;
    float C22 = stats[8]*Pinv - m2*m2;
    float w0 = W1[c], w1 = W1[256+c], w2 = W1[512+c];
    float mean = m0*w0 + m1*w1 + m2*w2 + b1[c];
    float var  = C00*w0*w0 + C11*w1*w1 + C22*w2*w2
               + 2.f*(C01*w0*w1 + C02*w0*w2 + C12*w1*w2);
    float a = g[c] * rsqrtf(var + LN_EPS);
    W1f[c]     = w0*a;
    W1f[256+c] = w1*a;
    W1f[512+c] = w2*a;
    b1f[c] = (b1[c] - mean)*a + b[c];
}

// ---------------------------------------------------------------------------
// transpose + bf16-cast both 256x256 W2 weights: Wt[n][k] = bf16(W[k][n])
// ---------------------------------------------------------------------------
__global__ void convert_w2_kernel(const float* __restrict__ Wp,
                                  const float* __restrict__ Wa,
                                  unsigned short* __restrict__ Wt_all) {
    int sel = blockIdx.x >> 8;
    int n = blockIdx.x & 255, k = threadIdx.x;
    const float* W = sel ? Wa : Wp;
    Wt_all[sel*65536 + n*256 + k] = f32_to_bf16_rne(W[k*256 + n]);
}

// ---------------------------------------------------------------------------
__global__ void convert_node_B(const float* __restrict__ sem_comb,
                               const float* __restrict__ nf_W,
                               unsigned short* __restrict__ Bt) {
    int n = blockIdx.x, t = threadIdx.x;
    Bt[n*1024 + t]       = f32_to_bf16_rne(sem_comb[t*256 + n]);
    Bt[n*1024 + 256 + t] = f32_to_bf16_rne(sem_comb[(256 + t)*256 + n]);
    Bt[n*1024 + 512 + t] = f32_to_bf16_rne(nf_W[(256 + t)*256 + n]);
    Bt[n*1024 + 768 + t] = f32_to_bf16_rne(nf_W[(512 + t)*256 + n]);
}

__global__ void convert_edge_B(const float* __restrict__ param_comb,
                               const float* __restrict__ anchor_comb,
                               const float* __restrict__ pose_comb,
                               unsigned short* __restrict__ Bt) {
    int n = blockIdx.x, t = threadIdx.x;
    Bt[n*320 + t] = f32_to_bf16_rne(param_comb[t*256 + n]);
    if (t < 64) {
        float v = 0.f;
        if (t < 24)      v = anchor_comb[t*256 + n];
        else if (t < 33) v = pose_comb[(t - 24)*256 + n];
        Bt[n*320 + 256 + t] = f32_to_bf16_rne(v);
    }
}

// ---------------------------------------------------------------------------
__global__ void small_matmul_kernel(const float* __restrict__ A, const float* __restrict__ B,
                                    float* __restrict__ C, int J) {
    int r = blockIdx.x, c = threadIdx.x;
    const float* Ar = A + (size_t)r * J;
    float acc = 0.f;
    for (int j = 0; j < J; j++) acc += Ar[j] * B[j*256 + c];
    C[r*256 + c] = acc;
}

__global__ void consts_kernel(const float* __restrict__ sem_b, const float* __restrict__ nf_W,
                              const float* __restrict__ nf_b,
                              const float* __restrict__ ep_b2, const float* __restrict__ ea_b,
                              const float* __restrict__ epo_b, const float* __restrict__ ef_W,
                              const float* __restrict__ ef_b,
                              float* __restrict__ node_const, float* __restrict__ edge_const) {
    int c = threadIdx.x;
    float nc = nf_b[c];
    for (int j = 0; j < 256; j++) nc += sem_b[j] * nf_W[j*256 + c];
    node_const[c] = nc;
    float ec = ef_b[c];
    for (int j = 0; j < 256; j++) ec += ep_b2[j] * ef_W[(256+j)*256 + c];
    for (int j = 0; j < 24;  j++) ec += ea_b[j]  * ef_W[(512+j)*256 + c];
    for (int j = 0; j < 9;   j++) ec += epo_b[j] * ef_W[(768+j)*256 + c];
    edge_const[c] = ec;
}

// ---------------------------------------------------------------------------
// point-cloud encoder v3 (merged pos+aff). Block owns 32 consecutive nodes;
// its sorted points/node-ids are read COALESCED (pre-gathered by scatter),
// double-buffered (loads issued early, LDS write late). Layer-1 A-fragments
// are computed IN REGISTERS per thread (3 FMA + relu + pack per element;
// W1f staged as float4 in 4 KB LDS, broadcast reads) -- no 34 KB u-tile.
// Segment-max accumulates in LDS (run-dedupe + ds atomicMax on non-neg bits),
// one coalesced atomic-free 32x256 write at the end.
// LDS ~39.9 KB, launch_bounds(256,3) -> 3 blocks/CU (vs 1 before).
// ---------------------------------------------------------------------------
#define SEG_STRIDE 260

__global__ __launch_bounds__(256, 3) void pce_seg_kernel(
    const float* __restrict__ xs_pos, const int* __restrict__ nd_pos,
    const int* __restrict__ be_pos,
    const float* __restrict__ xs_aff, const int* __restrict__ nd_aff,
    const int* __restrict__ be_aff,
    const float* __restrict__ W1f_all, const float* __restrict__ b1f_all,
    const unsigned short* __restrict__ Wt_all,
    const float* __restrict__ b2_pos, const float* __restrict__ b2_aff,
    float* __restrict__ seg_pos, float* __restrict__ seg_aff,
    int N, int nbPer)
{
    __shared__ unsigned int segacc[32 * SEG_STRIDE];   // 33280 B
    __shared__ float wcol4[256 * 4];                   // 4096 B  {w0,w1,w2,b1f}/col
    __shared__ float xsb[2][64 * 4];                   // 2048 B  padded float4/point
    __shared__ int   ndb[2][64];                       // 512 B

    int tid = threadIdx.x;
    bool isAff = (int)blockIdx.x >= nbPer;
    int blk = isAff ? (int)blockIdx.x - nbPer : (int)blockIdx.x;

    const float* xsf = isAff ? xs_aff : xs_pos;
    const int*   nds = isAff ? nd_aff : nd_pos;
    const int*   be  = isAff ? be_aff : be_pos;
    const unsigned short* Wt = Wt_all + (isAff ? 65536 : 0);
    const float* b2  = isAff ? b2_aff : b2_pos;
    float* seg = isAff ? seg_aff : seg_pos;

    int n0 = blk * 32;
    int nlast = min(n0 + 32, N) - 1;
    int s = (n0 == 0) ? 0 : be[n0 - 1];
    int e = be[nlast];

    for (int i = tid; i < 32 * SEG_STRIDE; i += 256) segacc[i] = 0u;
    {
        const float* W1f = W1f_all + (isAff ? 768 : 0);
        const float* b1f = b1f_all + (isAff ? 256 : 0);
        float4 w = make_float4(W1f[tid], W1f[256 + tid], W1f[512 + tid], b1f[tid]);
        *(float4*)&wcol4[tid * 4] = w;
    }

    int wave = tid >> 6, lane = tid & 63, lrow = lane & 15, lquad = lane >> 4;
    int nbase = wave * 64;
    float bias[4];
    #pragma unroll
    for (int ni = 0; ni < 4; ni++) bias[ni] = b2[nbase + ni*16 + lrow];

    // stage tile 0 (coalesced: thread -> one float of xsort, first 64 -> nd)
    {
        float rx = 0.f; int rn = -1;
        int p = s + (tid >> 2);
        if (p < e) rx = xsf[(size_t)p * 4 + (tid & 3)];
        if (tid < 64) { int q = s + tid; if (q < e) rn = nds[q] - n0; }
        xsb[0][tid] = rx;
        if (tid < 64) ndb[0][tid] = rn;
    }

    int buf = 0;
    for (int ts = s; ts < e; ts += 64, buf ^= 1) {
        // 1. issue next-tile loads (land during MFMA below)
        float rx = 0.f; int rn = -1;
        int ts2 = ts + 64;
        if (ts2 < e) {
            int p = ts2 + (tid >> 2);
            if (p < e) rx = xsf[(size_t)p * 4 + (tid & 3)];
            if (tid < 64) { int q = ts2 + tid; if (q < e) rn = nds[q] - n0; }
        }
        __syncthreads();   // buf[buf] staged; prev iter done with buf[buf^1]

        // 2. my 4 points (16B-aligned, broadcast across lquad groups)
        float4 pts[4];
        #pragma unroll
        for (int mi = 0; mi < 4; mi++)
            pts[mi] = *(const float4*)&xsb[buf][(mi*16 + lrow) * 4];

        floatx4 acc[4][4];
        #pragma unroll
        for (int mi = 0; mi < 4; mi++)
            #pragma unroll
            for (int ni = 0; ni < 4; ni++)
                acc[mi][ni] = (floatx4){0.f, 0.f, 0.f, 0.f};

        // 3. K loop: B frags from L2, A frags computed in registers
        #pragma unroll
        for (int kc = 0; kc < 8; kc++) {
            int cb = kc*32 + lquad*8;
            short8 b[4];
            #pragma unroll
            for (int ni = 0; ni < 4; ni++)
                b[ni] = *(const short8*)&Wt[(size_t)(nbase + ni*16 + lrow)*256 + cb];
            int w[4][4];
            #pragma unroll
            for (int jj = 0; jj < 4; jj++) {
                float4 wA = *(const float4*)&wcol4[(cb + 2*jj) * 4];
                float4 wB = *(const float4*)&wcol4[(cb + 2*jj + 1) * 4];
                #pragma unroll
                for (int mi = 0; mi < 4; mi++) {
                    float4 p = pts[mi];
                    float v0 = fmaxf(fmaf(p.x, wA.x, fmaf(p.y, wA.y, fmaf(p.z, wA.z, wA.w))), 0.f);
                    float v1 = fmaxf(fmaf(p.x, wB.x, fmaf(p.y, wB.y, fmaf(p.z, wB.z, wB.w))), 0.f);
                    w[mi][jj] = pack2_bf16(v0, v1);
                }
            }
            short8 a[4];
            #pragma unroll
            for (int mi = 0; mi < 4; mi++) {
                intx4 t = (intx4){w[mi][0], w[mi][1], w[mi][2], w[mi][3]};
                a[mi] = __builtin_bit_cast(short8, t);
            }
            #pragma unroll
            for (int mi = 0; mi < 4; mi++)
                #pragma unroll
                for (int ni = 0; ni < 4; ni++)
                    acc[mi][ni] = __builtin_amdgcn_mfma_f32_16x16x32_bf16(
                                      a[mi], b[ni], acc[mi][ni], 0, 0, 0);
        }

        // 4. write-late: stage next tile into the other buffer
        xsb[buf ^ 1][tid] = rx;
        if (tid < 64) ndb[buf ^ 1][tid] = rn;

        // 5. epilogue: relu(acc+bias) -> LDS segment max (run-dedupe, sorted)
        #pragma unroll
        for (int mi = 0; mi < 4; mi++) {
            int nd4[4];
            #pragma unroll
            for (int r = 0; r < 4; r++) nd4[r] = ndb[buf][mi*16 + lquad*4 + r];
            #pragma unroll
            for (int ni = 0; ni < 4; ni++) {
                int col = nbase + ni*16 + lrow;
                int cn = -1; float best = 0.f;
                #pragma unroll
                for (int r = 0; r < 4; r++) {
                    float y = fmaxf(acc[mi][ni][r] + bias[ni], 0.f);
                    if (nd4[r] != cn) {
                        if (cn >= 0)
                            atomicMax(&segacc[cn*SEG_STRIDE + col], __float_as_uint(best));
                        cn = nd4[r]; best = y;
                    } else {
                        best = fmaxf(best, y);
                    }
                }
                if (cn >= 0)
                    atomicMax(&segacc[cn*SEG_STRIDE + col], __float_as_uint(best));
            }
        }
    }

    __syncthreads();
    for (int t = 0; t < 32; t++) {
        int n = n0 + t;
        if (n <= nlast)
            seg[(size_t)n*256 + tid] = __uint_as_float(segacc[t*SEG_STRIDE + tid]);
    }
}

// ---------------------------------------------------------------------------
// LN reduce helpers: rows of 256 fp32 in LDS (given stride), write mean/rstd
// ---------------------------------------------------------------------------
__device__ __forceinline__ void ln_reduce_rows16(const float* __restrict__ rows, int stride,
                                                 float (*mr)[2], int tid) {
    int wave = tid >> 6, lane = tid & 63;
    for (int t = 0; t < 16; t++) {
        int n = wave*16 + t;
        const float* r = rows + n*stride;
        float v0 = r[lane], v1 = r[64+lane], v2 = r[128+lane], v3 = r[192+lane];
        float s = v0+v1+v2+v3;
        float q = v0*v0+v1*v1+v2*v2+v3*v3;
        for (int off = 32; off > 0; off >>= 1) {
            s += __shfl_down(s, off, 64);
            q += __shfl_down(q, off, 64);
        }
        if (lane == 0) {
            float mean = s * (1.f/256.f);
            mr[n][0] = mean;
            mr[n][1] = rsqrtf(q * (1.f/256.f) - mean*mean + LN_EPS);
        }
    }
}

__device__ __forceinline__ void ln_reduce_rows2(const float* __restrict__ rows, int stride,
                                                float (*mr)[2], int tid) {
    int wave = tid >> 6, lane = tid & 63;
    #pragma unroll
    for (int t = 0; t < 2; t++) {
        int n = wave*2 + t;
        const float* r = rows + n*stride;
        float v0 = r[lane], v1 = r[64+lane], v2 = r[128+lane], v3 = r[192+lane];
        float s = v0+v1+v2+v3;
        float q = v0*v0+v1*v1+v2*v2+v3*v3;
        for (int off = 32; off > 0; off >>= 1) {
            s += __shfl_down(s, off, 64);
            q += __shfl_down(q, off, 64);
        }
        if (lane == 0) {
            float mean = s * (1.f/256.f);
            mr[n][0] = mean;
            mr[n][1] = rsqrtf(q * (1.f/256.f) - mean*mean + LN_EPS);
        }
    }
}

// ---------------------------------------------------------------------------
// node MFMA (unchanged this round)
// ---------------------------------------------------------------------------
#define NA_STRIDE 264
#define NP_STRIDE 260

__global__ __launch_bounds__(256) void node_mfma_kernel(
    const float* __restrict__ x_sem, const float* __restrict__ h_pos,
    const float* __restrict__ h_aff,
    const unsigned short* __restrict__ BtN,
    const float* __restrict__ node_const,
    const float* __restrict__ ln_g, const float* __restrict__ ln_b,
    float* __restrict__ out, int N)
{
    __shared__ __align__(16) float smem[64 * NP_STRIDE];
    unsigned short* As = (unsigned short*)smem;
    float* pre = smem;
    __shared__ float mr[64][2];

    int tid = threadIdx.x;
    int base = blockIdx.x * 64;
    int nn = min(64, N - base);

    int wave  = tid >> 6;
    int lane  = tid & 63;
    int lrow  = lane & 15;
    int lquad = lane >> 4;
    int nbase = wave * 64;

    floatx4 acc[4][4];
    #pragma unroll
    for (int mi = 0; mi < 4; mi++)
        #pragma unroll
        for (int ni = 0; ni < 4; ni++)
            acc[mi][ni] = (floatx4){0.f, 0.f, 0.f, 0.f};

    #pragma unroll
    for (int chunk = 0; chunk < 4; chunk++) {
        const float* src; int sstride;
        if (chunk == 0)      { src = x_sem + (size_t)base*512;       sstride = 512; }
        else if (chunk == 1) { src = x_sem + (size_t)base*512 + 256; sstride = 512; }
        else if (chunk == 2) { src = h_pos + (size_t)base*256;       sstride = 256; }
        else                 { src = h_aff + (size_t)base*256;       sstride = 256; }

        for (int i = tid; i < 64*64; i += 256) {
            int row = i >> 6, c4 = (i & 63) * 4;
            float4 v = {0.f, 0.f, 0.f, 0.f};
            if (row < nn) v = *(const float4*)&src[(size_t)row*sstride + c4];
            ushort4 h;
            h.x = f32_to_bf16_rne(v.x); h.y = f32_to_bf16_rne(v.y);
            h.z = f32_to_bf16_rne(v.z); h.w = f32_to_bf16_rne(v.w);
            *(ushort4*)&As[row*NA_STRIDE + c4] = h;
        }
        __syncthreads();

        #pragma unroll
        for (int kc = 0; kc < 8; kc++) {
            int k0 = kc*32 + lquad*8;
            short8 a[4], b[4];
            #pragma unroll
            for (int mi = 0; mi < 4; mi++)
                a[mi] = *(const short8*)&As[(mi*16 + lrow)*NA_STRIDE + k0];
            #pragma unroll
            for (int ni = 0; ni < 4; ni++)
                b[ni] = *(const short8*)&BtN[(size_t)(nbase + ni*16 + lrow)*1024
                                             + chunk*256 + k0];
            #pragma unroll
            for (int mi = 0; mi < 4; mi++)
                #pragma unroll
                for (int ni = 0; ni < 4; ni++)
                    acc[mi][ni] = __builtin_amdgcn_mfma_f32_16x16x32_bf16(
                                      a[mi], b[ni], acc[mi][ni], 0, 0, 0);
        }
        __syncthreads();
    }

    #pragma unroll
    for (int ni = 0; ni < 4; ni++) {
        int col = nbase + ni*16 + lrow;
        float cst = node_const[col];
        #pragma unroll
        for (int mi = 0; mi < 4; mi++)
            #pragma unroll
            for (int r = 0; r < 4; r++) {
                int m = mi*16 + lquad*4 + r;
                pre[m*NP_STRIDE + col] = acc[mi][ni][r] + cst;
            }
    }
    __syncthreads();
    ln_reduce_rows16(pre, NP_STRIDE, mr, tid);
    __syncthreads();

    float gc = ln_g[tid], bc = ln_b[tid];
    for (int m = 0; m < 64; m++) {
        if (m < nn) {
            float y = (pre[m*NP_STRIDE + tid] - mr[m][0]) * mr[m][1] * gc + bc;
            out[(size_t)(base + m)*256 + tid] = fmaxf(y, 0.f);
        }
    }
}

// ---------------------------------------------------------------------------
// edge MFMA (unchanged this round)
// ---------------------------------------------------------------------------
#define EA_STRIDE 328
#define EP_STRIDE 260

__global__ __launch_bounds__(256) void edge_mfma_kernel(
    const int* __restrict__ etype, const float* __restrict__ eparam,
    const float* __restrict__ eanchor, const float* __restrict__ epose,
    const float* __restrict__ ep_W1, const float* __restrict__ ep_b1,
    const float* __restrict__ ep_ln_g, const float* __restrict__ ep_ln_b,
    const unsigned short* __restrict__ BtE,
    const float* __restrict__ type_proj, const float* __restrict__ edge_const,
    const float* __restrict__ ln_g, const float* __restrict__ ln_b,
    float* __restrict__ out, int E)
{
    __shared__ __align__(16) float smem[64 * EP_STRIDE];
    unsigned short* As = (unsigned short*)smem;
    float* pre = smem;
    float* h1tmp = smem + 12288;
    __shared__ float va[64][5];
    __shared__ int   ty[64];
    __shared__ float mr[64][2];
    __shared__ float mr8[8][2];

    int tid = threadIdx.x;
    int base = blockIdx.x * 64;
    int ne = min(64, E - base);

    for (int i = tid; i < 64*EA_STRIDE/4; i += 256)
        ((ushort4*)As)[i] = (ushort4){0, 0, 0, 0};
    if (tid < 64) {
        int e = tid;
        if (e < ne) {
            float d  = eparam[(size_t)(base+e)*3 + 0];
            float th = eparam[(size_t)(base+e)*3 + 1];
            float ph = eparam[(size_t)(base+e)*3 + 2];
            va[e][0] = fminf(fmaxf(d*10.f, -5.f), 5.f);
            va[e][1] = __sinf(th); va[e][2] = __cosf(th);
            va[e][3] = __sinf(ph); va[e][4] = __cosf(ph);
            ty[e] = etype[base+e];
        } else {
            va[e][0]=va[e][1]=va[e][2]=va[e][3]=va[e][4]=0.f; ty[e]=0;
        }
    }
    __syncthreads();

    for (int i = tid; i < 64*24; i += 256) {
        float v = (i < ne*24) ? eanchor[(size_t)base*24 + i] : 0.f;
        As[(i/24)*EA_STRIDE + 256 + (i % 24)] = f32_to_bf16_rne(v);
    }
    for (int i = tid; i < 64*9; i += 256) {
        float v = (i < ne*9) ? epose[(size_t)base*9 + i] : 0.f;
        As[(i/9)*EA_STRIDE + 280 + (i % 9)] = f32_to_bf16_rne(v);
    }

    int c = tid;
    float w0=ep_W1[c], w1=ep_W1[256+c], w2=ep_W1[512+c], w3=ep_W1[768+c], w4=ep_W1[1024+c];
    float bb = ep_b1[c];
    float gc1 = ep_ln_g[c], bc1 = ep_ln_b[c];
    for (int g = 0; g < 8; g++) {
        float t[8];
        #pragma unroll
        for (int e = 0; e < 8; e++) {
            int ge = g*8 + e;
            t[e] = va[ge][0]*w0 + va[ge][1]*w1 + va[ge][2]*w2 + va[ge][3]*w3
                 + va[ge][4]*w4 + bb;
            h1tmp[e*EP_STRIDE + c] = t[e];
        }
        __syncthreads();
        ln_reduce_rows2(h1tmp, EP_STRIDE, mr8, tid);
        __syncthreads();
        #pragma unroll
        for (int e = 0; e < 8; e++) {
            float y = fmaxf((t[e] - mr8[e][0]) * mr8[e][1] * gc1 + bc1, 0.f);
            As[(g*8 + e)*EA_STRIDE + c] = f32_to_bf16_rne(y);
        }
        __syncthreads();
    }

    int wave  = tid >> 6;
    int lane  = tid & 63;
    int lrow  = lane & 15;
    int lquad = lane >> 4;
    int nbase = wave * 64;

    floatx4 acc[4][4];
    #pragma unroll
    for (int mi = 0; mi < 4; mi++)
        #pragma unroll
        for (int ni = 0; ni < 4; ni++)
            acc[mi][ni] = (floatx4){0.f, 0.f, 0.f, 0.f};

    #pragma unroll
    for (int kc = 0; kc < 10; kc++) {
        int k0 = kc*32 + lquad*8;
        short8 a[4], b[4];
        #pragma unroll
        for (int mi = 0; mi < 4; mi++)
            a[mi] = *(const short8*)&As[(mi*16 + lrow)*EA_STRIDE + k0];
        #pragma unroll
        for (int ni = 0; ni < 4; ni++)
            b[ni] = *(const short8*)&BtE[(size_t)(nbase + ni*16 + lrow)*320 + k0];
        #pragma unroll
        for (int mi = 0; mi < 4; mi++)
            #pragma unroll
            for (int ni = 0; ni < 4; ni++)
                acc[mi][ni] = __builtin_amdgcn_mfma_f32_16x16x32_bf16(
                                  a[mi], b[ni], acc[mi][ni], 0, 0, 0);
    }
    __syncthreads();

    #pragma unroll
    for (int ni = 0; ni < 4; ni++) {
        int col = nbase + ni*16 + lrow;
        float cst = edge_const[col];
        #pragma unroll
        for (int mi = 0; mi < 4; mi++)
            #pragma unroll
            for (int r = 0; r < 4; r++) {
                int m = mi*16 + lquad*4 + r;
                pre[m*EP_STRIDE + col] = acc[mi][ni][r] + cst
                                       + type_proj[ty[m]*256 + col];
            }
    }
    __syncthreads();
    ln_reduce_rows16(pre, EP_STRIDE, mr, tid);
    __syncthreads();

    float gc = ln_g[tid], bc = ln_b[tid];
    for (int m = 0; m < 64; m++) {
        if (m < ne) {
            float y = (pre[m*EP_STRIDE + tid] - mr[m][0]) * mr[m][1] * gc + bc;
            out[(size_t)(base + m)*256 + tid] = fmaxf(y, 0.f);
        }
    }
}

// ---------------------------------------------------------------------------
extern "C" void kernel_launch(void* const* d_in, const int* in_sizes, int n_in,
                              void* d_out, int out_size, void* d_ws, size_t ws_size,
                              hipStream_t stream)
{
    const float* x_sem     = (const float*)d_in[0];
    const float* x_pos     = (const float*)d_in[1];
    const int*   pos_bidx  = (const int*)  d_in[2];
    const float* x_aff     = (const float*)d_in[3];
    const int*   aff_bidx  = (const int*)  d_in[4];
    const int*   edge_type = (const int*)  d_in[5];
    const float* edge_param  = (const float*)d_in[6];
    const float* edge_anchor = (const float*)d_in[7];
    const float* edge_pose   = (const float*)d_in[8];
    const float* sem_W  = (const float*)d_in[10];
    const float* sem_b  = (const float*)d_in[11];
    const float* pos_W1 = (const float*)d_in[12];
    const float* pos_b1 = (const float*)d_in[13];
    const float* pos_bn_g = (const float*)d_in[14];
    const float* pos_bn_b = (const float*)d_in[15];
    const float* pos_W2 = (const float*)d_in[16];
    const float* pos_b2 = (const float*)d_in[17];
    const float* aff_W1 = (const float*)d_in[18];
    const float* aff_b1 = (const float*)d_in[19];
    const float* aff_bn_g = (const float*)d_in[20];
    const float* aff_bn_b = (const float*)d_in[21];
    const float* aff_W2 = (const float*)d_in[22];
    const float* aff_b2 = (const float*)d_in[23];
    const float* nf_W   = (const float*)d_in[24];
    const float* nf_b   = (const float*)d_in[25];
    const float* nf_ln_g = (const float*)d_in[26];
    const float* nf_ln_b = (const float*)d_in[27];
    const float* et_emb = (const float*)d_in[28];
    const float* ep_W1  = (const float*)d_in[29];
    const float* ep_b1  = (const float*)d_in[30];
    const float* ep_ln_g = (const float*)d_in[31];
    const float* ep_ln_b = (const float*)d_in[32];
    const float* ep_W2  = (const float*)d_in[33];
    const float* ep_b2  = (const float*)d_in[34];
    const float* ea_W   = (const float*)d_in[35];
    const float* ea_b   = (const float*)d_in[36];
    const float* epo_W  = (const float*)d_in[37];
    const float* epo_b  = (const float*)d_in[38];
    const float* ef_W   = (const float*)d_in[39];
    const float* ef_b   = (const float*)d_in[40];
    const float* ef_ln_g = (const float*)d_in[41];
    const float* ef_ln_b = (const float*)d_in[42];

    int N  = in_sizes[0] / 512;
    int Pp = in_sizes[1] / 3;
    int Pa = in_sizes[3] / 3;
    int E  = in_sizes[5];
    int N2 = (N + 4095) & ~4095;          // cnt arrays padded for int4 scan

    float* ws = (float*)d_ws;
    size_t off = 0;
    float* h_pos = ws + off;      off += (size_t)N*256;
    float* h_aff = ws + off;      off += (size_t)N*256;
    float* stats = ws + off;      off += 32;              // [0..15]=pos,[16..31]=aff
    int* cnt_pos = (int*)(ws+off); off += N2;
    int* cnt_aff = (int*)(ws+off); off += N2;
    int* base_pos = (int*)(ws+off); off += N;
    int* base_aff = (int*)(ws+off); off += N;
    off = (off + 3) & ~(size_t)3;                          // 16B align for float4
    float* xs_pos = ws + off;     off += (size_t)Pp*4;
    int* nd_pos = (int*)(ws+off); off += Pp;
    off = (off + 3) & ~(size_t)3;
    float* xs_aff = ws + off;     off += (size_t)Pa*4;
    int* nd_aff = (int*)(ws+off); off += Pa;
    off = (off + 3) & ~(size_t)3;
    float* W1f_all = ws + off;    off += 1536;            // pos 768 | aff 768
    float* b1f_all = ws + off;    off += 512;             // pos 256 | aff 256
    float* sem_comb   = ws + off; off += 512*256;
    float* param_comb = ws + off; off += 256*256;
    float* anchor_comb= ws + off; off += 24*256;
    float* pose_comb  = ws + off; off += 9*256;
    float* type_proj  = ws + off; off += 7*256;
    float* node_const = ws + off; off += 256;
    float* edge_const = ws + off; off += 256;
    unsigned short* Wt_all = (unsigned short*)(ws + off);  // pos 64K | aff 64K shorts
    unsigned short* BtN    = Wt_all + 2*65536;
    unsigned short* BtE    = BtN + 256*1024;

    // zero stats + padded CSR counters (contiguous region)
    (void)hipMemsetAsync(stats, 0, (32 + 2*(size_t)N2) * sizeof(int), stream);

    stats_kernel<<<1024, 256, 0, stream>>>(x_pos, Pp, x_aff, Pa, stats);
    count_kernel<<<1024, 256, 0, stream>>>(pos_bidx, aff_bidx, Pp, Pa, cnt_pos, cnt_aff);
    scan2_kernel<<<2, 1024, 0, stream>>>(cnt_pos, cnt_aff, base_pos, base_aff, N);
    scatter_kernel<<<1024, 256, 0, stream>>>(x_pos, pos_bidx, Pp, x_aff, aff_bidx, Pa,
                                             base_pos, base_aff,
                                             (float4*)xs_pos, nd_pos,
                                             (float4*)xs_aff, nd_aff);

    fold_bn_kernel<<<2, 256, 0, stream>>>(stats,
                                          pos_W1, pos_b1, pos_bn_g, pos_bn_b,
                                          aff_W1, aff_b1, aff_bn_g, aff_bn_b,
                                          1.f/(float)Pp, 1.f/(float)Pa,
                                          W1f_all, b1f_all);
    convert_w2_kernel<<<512, 256, 0, stream>>>(pos_W2, aff_W2, Wt_all);

    small_matmul_kernel<<<512, 256, 0, stream>>>(sem_W,  nf_W,            sem_comb,   256);
    small_matmul_kernel<<<256, 256, 0, stream>>>(ep_W2,  ef_W + 256*256,  param_comb, 256);
    small_matmul_kernel<<<24,  256, 0, stream>>>(ea_W,   ef_W + 512*256,  anchor_comb,256);
    small_matmul_kernel<<<9,   256, 0, stream>>>(epo_W,  ef_W + 768*256,  pose_comb,  256);
    small_matmul_kernel<<<7,   256, 0, stream>>>(et_emb, ef_W,            type_proj,  256);
    consts_kernel<<<1, 256, 0, stream>>>(sem_b, nf_W, nf_b, ep_b2, ea_b, epo_b, ef_W, ef_b,
                                         node_const, edge_const);
    convert_node_B<<<256, 256, 0, stream>>>(sem_comb, nf_W, BtN);
    convert_edge_B<<<256, 256, 0, stream>>>(param_comb, anchor_comb, pose_comb, BtE);

    // after scatter, base_* hold END offsets per node
    int nbPer = (N + 31) / 32;
    pce_seg_kernel<<<2*nbPer, 256, 0, stream>>>(xs_pos, nd_pos, base_pos,
                                                xs_aff, nd_aff, base_aff,
                                                W1f_all, b1f_all, Wt_all,
                                                pos_b2, aff_b2,
                                                h_pos, h_aff, N, nbPer);

    node_mfma_kernel<<<(N + 63)/64, 256, 0, stream>>>(x_sem, h_pos, h_aff, BtN, node_const,
                                                      nf_ln_g, nf_ln_b,
                                                      (float*)d_out, N);
    edge_mfma_kernel<<<(E + 63)/64, 256, 0, stream>>>(edge_type, edge_param, edge_anchor,
                                                      edge_pose, ep_W1, ep_b1,
                                                      ep_ln_g, ep_ln_b, BtE,
                                                      type_proj, edge_const,
                                                      ef_ln_g, ef_ln_b,
                                                      (float*)d_out + (size_t)N*256, E);
}

// Round 4
// 2021.024 us; speedup vs baseline: 1.3376x; 1.0629x over previous
//
#include <hip/hip_runtime.h>
#include <math.h>

#define LN_EPS 1e-5f

typedef __attribute__((ext_vector_type(8))) short short8;   // 8 bf16 = 4 VGPRs
typedef __attribute__((ext_vector_type(4))) float floatx4;  // MFMA C/D
typedef __attribute__((ext_vector_type(4))) int   intx4;

__device__ __forceinline__ unsigned short f32_to_bf16_rne(float v) {
    unsigned int u = __float_as_uint(v);
    return (unsigned short)((u + 0x7FFFu + ((u >> 16) & 1u)) >> 16);
}

// pack two fp32 -> one dword of 2 bf16 (RNE), lo in bits 0..15
__device__ __forceinline__ int pack2_bf16(float lo, float hi) {
    unsigned int r = ((unsigned int)f32_to_bf16_rne(hi) << 16)
                   |  (unsigned int)f32_to_bf16_rne(lo);
    return (int)r;
}

// ---------------------------------------------------------------------------
// stats (merged pos+aff): sum(x_i), sum(x_i x_j) over (P,3) -> 9 floats each
// ---------------------------------------------------------------------------
__global__ __launch_bounds__(256) void stats_kernel(const float* __restrict__ xp, int Pp,
                                                    const float* __restrict__ xa, int Pa,
                                                    float* __restrict__ stats) {
    int half = gridDim.x >> 1;
    bool aff = (int)blockIdx.x >= half;
    const float* x = aff ? xa : xp;
    int P = aff ? Pa : Pp;
    float* st = stats + (aff ? 16 : 0);
    int b = aff ? blockIdx.x - half : blockIdx.x;
    int tid = b * 256 + threadIdx.x;
    int stride = half * 256;
    float s[9] = {0.f,0.f,0.f,0.f,0.f,0.f,0.f,0.f,0.f};
    for (int i = tid; i < P; i += stride) {
        float a = x[i*3+0], bb = x[i*3+1], c = x[i*3+2];
        s[0]+=a; s[1]+=bb; s[2]+=c;
        s[3]+=a*a; s[4]+=a*bb; s[5]+=a*c;
        s[6]+=bb*bb; s[7]+=bb*c; s[8]+=c*c;
    }
    #pragma unroll
    for (int j = 0; j < 9; j++) {
        float v = s[j];
        for (int off = 32; off > 0; off >>= 1) v += __shfl_down(v, off, 64);
        if ((threadIdx.x & 63) == 0) atomicAdd(&st[j], v);
    }
}

// ---------------------------------------------------------------------------
// CSR grouping: count -> scan -> scatter
// ---------------------------------------------------------------------------
__global__ __launch_bounds__(256) void count_kernel(const int* __restrict__ bp,
                                                    const int* __restrict__ ba,
                                                    int Pp, int Pa,
                                                    int* __restrict__ cp,
                                                    int* __restrict__ ca) {
    int half = gridDim.x >> 1;
    bool isAff = (int)blockIdx.x >= half;
    const int* bidx = isAff ? ba : bp;
    int* cnt        = isAff ? ca : cp;
    int P           = isAff ? Pa : Pp;
    int b = isAff ? blockIdx.x - half : blockIdx.x;
    int stride = half * 256;
    for (int i = b*256 + threadIdx.x; i < P; i += stride)
        atomicAdd(&cnt[bidx[i]], 1);
}

// exclusive scan, 1024 threads, int4 per thread (cnt padded to N2 with zeros)
__global__ __launch_bounds__(1024) void scan2_kernel(const int* __restrict__ cnt_pos,
                                                     const int* __restrict__ cnt_aff,
                                                     int* __restrict__ base_pos,
                                                     int* __restrict__ base_aff, int N) {
    const int* cnt = blockIdx.x ? cnt_aff : cnt_pos;
    int* base      = blockIdx.x ? base_aff : base_pos;
    __shared__ int wsum[16];
    __shared__ int carry;
    int tid = threadIdx.x, lane = tid & 63, wave = tid >> 6;
    if (tid == 0) carry = 0;
    __syncthreads();
    for (int t0 = 0; t0 < N; t0 += 4096) {
        int i4 = t0 + tid * 4;
        int4 v = *(const int4*)&cnt[i4];
        int tt = v.x + v.y + v.z + v.w;
        int s = tt;
        #pragma unroll
        for (int off = 1; off < 64; off <<= 1) {
            int u = __shfl_up(s, off, 64);
            if (lane >= off) s += u;
        }
        __syncthreads();
        if (lane == 63) wsum[wave] = s;
        __syncthreads();
        int c0 = carry;
        int woff = c0, tot = 0;
        #pragma unroll
        for (int w = 0; w < 16; w++) { int z = wsum[w]; tot += z; if (w < wave) woff += z; }
        int excl = woff + s - tt;
        if (i4     < N) base[i4]     = excl;
        if (i4 + 1 < N) base[i4 + 1] = excl + v.x;
        if (i4 + 2 < N) base[i4 + 2] = excl + v.x + v.y;
        if (i4 + 3 < N) base[i4 + 3] = excl + v.x + v.y + v.z;
        __syncthreads();
        if (tid == 0) carry = c0 + tot;
    }
}

// scatter: pos = base[n]++; xsort[pos] = {x,y,z,0}; ndsort[pos] = n.
__global__ __launch_bounds__(256) void scatter_kernel(
    const float* __restrict__ xp, const int* __restrict__ bp, int Pp,
    const float* __restrict__ xa, const int* __restrict__ ba, int Pa,
    int* __restrict__ base_pos, int* __restrict__ base_aff,
    float4* __restrict__ xs_pos, int* __restrict__ nd_pos,
    float4* __restrict__ xs_aff, int* __restrict__ nd_aff) {
    int half = gridDim.x >> 1;
    bool isAff = (int)blockIdx.x >= half;
    const float* x  = isAff ? xa : xp;
    const int* bidx = isAff ? ba : bp;
    int P           = isAff ? Pa : Pp;
    int* base       = isAff ? base_aff : base_pos;
    float4* xs      = isAff ? xs_aff : xs_pos;
    int* nd         = isAff ? nd_aff : nd_pos;
    int b = isAff ? blockIdx.x - half : blockIdx.x;
    int stride = half * 256;
    for (int i = b*256 + threadIdx.x; i < P; i += stride) {
        int n = bidx[i];
        int pos = atomicAdd(&base[n], 1);
        float4 v;
        v.x = x[i*3+0]; v.y = x[i*3+1]; v.z = x[i*3+2]; v.w = 0.f;
        xs[pos] = v;
        nd[pos] = n;
    }
}

// ---------------------------------------------------------------------------
// fold BN into W1/b1 (merged pos/aff)
// ---------------------------------------------------------------------------
__global__ void fold_bn_kernel(const float* __restrict__ stats_all,
                               const float* __restrict__ W1p, const float* __restrict__ b1p,
                               const float* __restrict__ gp,  const float* __restrict__ bgp,
                               const float* __restrict__ W1a, const float* __restrict__ b1a,
                               const float* __restrict__ ga,  const float* __restrict__ bga,
                               float Pinv_p, float Pinv_a,
                               float* __restrict__ W1f_all, float* __restrict__ b1f_all) {
    int sel = blockIdx.x;
    const float* stats = stats_all + sel*16;
    const float* W1 = sel ? W1a : W1p;
    const float* b1 = sel ? b1a : b1p;
    const float* g  = sel ? ga  : gp;
    const float* b  = sel ? bga : bgp;
    float Pinv = sel ? Pinv_a : Pinv_p;
    float* W1f = W1f_all + sel*768;
    float* b1f = b1f_all + sel*256;
    int c = threadIdx.x;
    float m0 = stats[0]*Pinv, m1 = stats[1]*Pinv, m2 = stats[2]*Pinv;
    float C00 = stats[3]*Pinv - m0*m0;
    float C01 = stats[4]*Pinv - m0*m1;
    float C02 = stats[5]*Pinv - m0*m2;
    float C11 = stats[6]*Pinv - m1*m1;
    float C12 = stats[7]*Pinv - m1*m2;
    float C22 = stats[8]*Pinv - m2*m2;
    float w0 = W1[c], w1 = W1[256+c], w2 = W1[512+c];
    float mean = m0*w0 + m1*w1 + m2*w2 + b1[c];
    float var  = C00*w0*w0 + C11*w1*w1 + C22*w2*w2
               + 2.f*(C01*w0*w1 + C02*w0*w2 + C12*w1*w2);
    float a = g[c] * rsqrtf(var + LN_EPS);
    W1f[c]     = w0*a;
    W1f[256+c] = w1*a;
    W1f[512+c] = w2*a;
    b1f[c] = (b1[c] - mean)*a + b[c];
}

// ---------------------------------------------------------------------------
__global__ void convert_w2_kernel(const float* __restrict__ Wp,
                                  const float* __restrict__ Wa,
                                  unsigned short* __restrict__ Wt_all) {
    int sel = blockIdx.x >> 8;
    int n = blockIdx.x & 255, k = threadIdx.x;
    const float* W = sel ? Wa : Wp;
    Wt_all[sel*65536 + n*256 + k] = f32_to_bf16_rne(W[k*256 + n]);
}

__global__ void convert_node_B(const float* __restrict__ sem_comb,
                               const float* __restrict__ nf_W,
                               unsigned short* __restrict__ Bt) {
    int n = blockIdx.x, t = threadIdx.x;
    Bt[n*1024 + t]       = f32_to_bf16_rne(sem_comb[t*256 + n]);
    Bt[n*1024 + 256 + t] = f32_to_bf16_rne(sem_comb[(256 + t)*256 + n]);
    Bt[n*1024 + 512 + t] = f32_to_bf16_rne(nf_W[(256 + t)*256 + n]);
    Bt[n*1024 + 768 + t] = f32_to_bf16_rne(nf_W[(512 + t)*256 + n]);
}

__global__ void convert_edge_B(const float* __restrict__ param_comb,
                               const float* __restrict__ anchor_comb,
                               const float* __restrict__ pose_comb,
                               unsigned short* __restrict__ Bt) {
    int n = blockIdx.x, t = threadIdx.x;
    Bt[n*320 + t] = f32_to_bf16_rne(param_comb[t*256 + n]);
    if (t < 64) {
        float v = 0.f;
        if (t < 24)      v = anchor_comb[t*256 + n];
        else if (t < 33) v = pose_comb[(t - 24)*256 + n];
        Bt[n*320 + 256 + t] = f32_to_bf16_rne(v);
    }
}

// ---------------------------------------------------------------------------
__global__ void small_matmul_kernel(const float* __restrict__ A, const float* __restrict__ B,
                                    float* __restrict__ C, int J) {
    int r = blockIdx.x, c = threadIdx.x;
    const float* Ar = A + (size_t)r * J;
    float acc = 0.f;
    for (int j = 0; j < J; j++) acc += Ar[j] * B[j*256 + c];
    C[r*256 + c] = acc;
}

__global__ void consts_kernel(const float* __restrict__ sem_b, const float* __restrict__ nf_W,
                              const float* __restrict__ nf_b,
                              const float* __restrict__ ep_b2, const float* __restrict__ ea_b,
                              const float* __restrict__ epo_b, const float* __restrict__ ef_W,
                              const float* __restrict__ ef_b,
                              float* __restrict__ node_const, float* __restrict__ edge_const) {
    int c = threadIdx.x;
    float nc = nf_b[c];
    for (int j = 0; j < 256; j++) nc += sem_b[j] * nf_W[j*256 + c];
    node_const[c] = nc;
    float ec = ef_b[c];
    for (int j = 0; j < 256; j++) ec += ep_b2[j] * ef_W[(256+j)*256 + c];
    for (int j = 0; j < 24;  j++) ec += ea_b[j]  * ef_W[(512+j)*256 + c];
    for (int j = 0; j < 9;   j++) ec += epo_b[j] * ef_W[(768+j)*256 + c];
    edge_const[c] = ec;
}

// ---------------------------------------------------------------------------
// point-cloud encoder v4: block = 32 nodes x 64 output cols (4 col-blocks per
// node-group, 2 encoders). B-slice (64x256 bf16 = 32 KB) staged ONCE per block
// into XOR-swizzled LDS (tile-invariant -> kills the 870 MB HBM re-fetch).
// Waves M-split: wave owns 16 points/tile; layer-1 A-frags in registers
// (each (p,k) computed once per block). Double-buffered coalesced point loads.
// LDS ~47 KB -> 3 blocks/CU. XCD swizzle co-locates the 4 col-siblings.
// ---------------------------------------------------------------------------
#define SEGA_STRIDE 66

__global__ __launch_bounds__(256, 3) void pce_seg_kernel(
    const float* __restrict__ xs_pos, const int* __restrict__ nd_pos,
    const int* __restrict__ be_pos,
    const float* __restrict__ xs_aff, const int* __restrict__ nd_aff,
    const int* __restrict__ be_aff,
    const float* __restrict__ W1f_all, const float* __restrict__ b1f_all,
    const unsigned short* __restrict__ Wt_all,
    const float* __restrict__ b2_pos, const float* __restrict__ b2_aff,
    float* __restrict__ seg_pos, float* __restrict__ seg_aff,
    int N, int nbPer)
{
    __shared__ __align__(16) short Bs[64 * 256];            // 32 KB swizzled
    __shared__ unsigned int segacc[32 * SEGA_STRIDE];       // 8448 B
    __shared__ __align__(16) float wk[256 * 4];             // 4 KB swizzled
    __shared__ float xsb[2][64 * 4];                        // 2 KB
    __shared__ int   ndb[2][64];                            // 512 B

    int tid = threadIdx.x;

    // bijective XCD swizzle (m204): consecutive logical blocks share an XCD
    int nwg = gridDim.x;
    int q8 = nwg >> 3, r8 = nwg & 7;
    int xcd = blockIdx.x & 7, loc = blockIdx.x >> 3;
    int wgid = (xcd < r8 ? xcd*(q8+1) : r8*(q8+1) + (xcd - r8)*q8) + loc;

    int per = nbPer * 4;
    bool isAff = wgid >= per;
    int rem = isAff ? wgid - per : wgid;
    int blk = rem >> 2;
    int colbase = (rem & 3) * 64;

    const float* xsf = isAff ? xs_aff : xs_pos;
    const int*   nds = isAff ? nd_aff : nd_pos;
    const int*   be  = isAff ? be_aff : be_pos;
    const unsigned short* Wt = Wt_all + (isAff ? 65536 : 0) + colbase*256;
    const float* b2  = isAff ? b2_aff : b2_pos;
    float* seg = isAff ? seg_aff : seg_pos;

    int n0 = blk * 32;
    int nlast = min(n0 + 32, N) - 1;
    int s = (n0 == 0) ? 0 : be[n0 - 1];
    int e = be[nlast];

    for (int i = tid; i < 32 * SEGA_STRIDE; i += 256) segacc[i] = 0u;
    {
        const float* W1f = W1f_all + (isAff ? 768 : 0);
        const float* b1f = b1f_all + (isAff ? 256 : 0);
        float4 w = make_float4(W1f[tid], W1f[256 + tid], W1f[512 + tid], b1f[tid]);
        *(float4*)&wk[(tid * 4) ^ ((tid & 24) >> 1)] = w;   // bank-spread per lquad
    }
    // stage B-slice once: 64 cols x 256 k, XOR-swizzle ((col&7)<<3 shorts)
    #pragma unroll
    for (int i = 0; i < 8; i++) {
        int j = i * 256 + tid;                 // 2048 short8 groups
        int col = j >> 5, k8 = (j & 31) << 3;
        short8 v = *(const short8*)&Wt[col * 256 + k8];
        *(short8*)&Bs[(col * 256 + k8) ^ ((col & 7) << 3)] = v;
    }

    int wave = tid >> 6, lane = tid & 63, lrow = lane & 15, lquad = lane >> 4;
    int pbase = wave * 16;
    float bias[4];
    #pragma unroll
    for (int ni = 0; ni < 4; ni++) bias[ni] = b2[colbase + ni*16 + lrow];

    // stage tile 0
    {
        float rx = 0.f; int rn = -1;
        int p = s + (tid >> 2);
        if (p < e) rx = xsf[(size_t)p * 4 + (tid & 3)];
        if (tid < 64) { int qq = s + tid; if (qq < e) rn = nds[qq] - n0; }
        xsb[0][tid] = rx;
        if (tid < 64) ndb[0][tid] = rn;
    }

    int buf = 0;
    for (int ts = s; ts < e; ts += 64, buf ^= 1) {
        // issue next-tile loads early
        float rx = 0.f; int rn = -1;
        int ts2 = ts + 64;
        if (ts2 < e) {
            int p = ts2 + (tid >> 2);
            if (p < e) rx = xsf[(size_t)p * 4 + (tid & 3)];
            if (tid < 64) { int qq = ts2 + tid; if (qq < e) rn = nds[qq] - n0; }
        }
        __syncthreads();   // tile buf staged (incl. B/wk on first iter)

        float4 pt = *(const float4*)&xsb[buf][(pbase + lrow) * 4];  // broadcast
        int nd4[4];
        #pragma unroll
        for (int r = 0; r < 4; r++) nd4[r] = ndb[buf][pbase + lquad*4 + r];

        floatx4 acc[4];
        #pragma unroll
        for (int ni = 0; ni < 4; ni++) acc[ni] = (floatx4){0.f, 0.f, 0.f, 0.f};

        #pragma unroll
        for (int kc = 0; kc < 8; kc++) {
            int kb = kc*32 + lquad*8;
            short8 bfr[4];
            #pragma unroll
            for (int ni = 0; ni < 4; ni++) {
                int c = ni*16 + lrow;
                bfr[ni] = *(const short8*)&Bs[(c*256 + kb) ^ ((c & 7) << 3)];
            }
            int af[4];
            #pragma unroll
            for (int j2 = 0; j2 < 4; j2++) {
                int c0 = kb + 2*j2, c1 = c0 + 1;
                float4 wA = *(const float4*)&wk[(c0*4) ^ ((c0 & 24) >> 1)];
                float4 wB = *(const float4*)&wk[(c1*4) ^ ((c1 & 24) >> 1)];
                float v0 = fmaxf(fmaf(pt.x, wA.x, fmaf(pt.y, wA.y, fmaf(pt.z, wA.z, wA.w))), 0.f);
                float v1 = fmaxf(fmaf(pt.x, wB.x, fmaf(pt.y, wB.y, fmaf(pt.z, wB.z, wB.w))), 0.f);
                af[j2] = pack2_bf16(v0, v1);
            }
            short8 a = __builtin_bit_cast(short8, (intx4){af[0], af[1], af[2], af[3]});
            #pragma unroll
            for (int ni = 0; ni < 4; ni++)
                acc[ni] = __builtin_amdgcn_mfma_f32_16x16x32_bf16(a, bfr[ni], acc[ni], 0, 0, 0);
        }

        // write-late: stage next tile into other buffer
        xsb[buf ^ 1][tid] = rx;
        if (tid < 64) ndb[buf ^ 1][tid] = rn;

        // epilogue: relu(acc+bias) -> LDS segment max (run-dedupe, sorted rows)
        #pragma unroll
        for (int ni = 0; ni < 4; ni++) {
            int colloc = ni*16 + lrow;
            int cn = -1; float best = 0.f;
            #pragma unroll
            for (int r = 0; r < 4; r++) {
                float y = fmaxf(acc[ni][r] + bias[ni], 0.f);
                if (nd4[r] != cn) {
                    if (cn >= 0)
                        atomicMax(&segacc[cn*SEGA_STRIDE + colloc], __float_as_uint(best));
                    cn = nd4[r]; best = y;
                } else {
                    best = fmaxf(best, y);
                }
            }
            if (cn >= 0)
                atomicMax(&segacc[cn*SEGA_STRIDE + colloc], __float_as_uint(best));
        }
    }

    __syncthreads();
    for (int i = tid; i < 32 * 64; i += 256) {
        int t = i >> 6, c = i & 63;
        int n = n0 + t;
        if (n <= nlast)
            seg[(size_t)n*256 + colbase + c] = __uint_as_float(segacc[t*SEGA_STRIDE + c]);
    }
}

// ---------------------------------------------------------------------------
// LN reduce helper for the edge h1 phase (rows of 256 fp32 in LDS)
// ---------------------------------------------------------------------------
__device__ __forceinline__ void ln_reduce_rows2(const float* __restrict__ rows, int stride,
                                                float (*mr)[2], int tid) {
    int wave = tid >> 6, lane = tid & 63;
    #pragma unroll
    for (int t = 0; t < 2; t++) {
        int n = wave*2 + t;
        const float* r = rows + n*stride;
        float v0 = r[lane], v1 = r[64+lane], v2 = r[128+lane], v3 = r[192+lane];
        float s = v0+v1+v2+v3;
        float q = v0*v0+v1*v1+v2*v2+v3*v3;
        for (int off = 32; off > 0; off >>= 1) {
            s += __shfl_down(s, off, 64);
            q += __shfl_down(q, off, 64);
        }
        if (lane == 0) {
            float mean = s * (1.f/256.f);
            mr[n][0] = mean;
            mr[n][1] = rsqrtf(q * (1.f/256.f) - mean*mean + LN_EPS);
        }
    }
}

// ---------------------------------------------------------------------------
// node MFMA v2: LN computed from accumulator registers (shfl_xor row partials
// -> 2.5 KB LDS combine -> direct 64B-aligned stores). No 66 KB pre buffer:
// LDS 36.3 KB -> 3 blocks/CU.
// ---------------------------------------------------------------------------
#define NA_STRIDE 264

__global__ __launch_bounds__(256, 3) void node_mfma_kernel(
    const float* __restrict__ x_sem, const float* __restrict__ h_pos,
    const float* __restrict__ h_aff,
    const unsigned short* __restrict__ BtN,
    const float* __restrict__ node_const,
    const float* __restrict__ ln_g, const float* __restrict__ ln_b,
    float* __restrict__ out, int N)
{
    __shared__ __align__(16) unsigned short As[64 * NA_STRIDE];  // 33792 B
    __shared__ float rowred[4][64][2];                           // 2048 B
    __shared__ float mr[64][2];                                  // 512 B

    int tid = threadIdx.x;
    int base = blockIdx.x * 64;
    int nn = min(64, N - base);

    int wave  = tid >> 6;
    int lane  = tid & 63;
    int lrow  = lane & 15;
    int lquad = lane >> 4;
    int nbase = wave * 64;

    floatx4 acc[4][4];
    #pragma unroll
    for (int mi = 0; mi < 4; mi++)
        #pragma unroll
        for (int ni = 0; ni < 4; ni++)
            acc[mi][ni] = (floatx4){0.f, 0.f, 0.f, 0.f};

    #pragma unroll
    for (int chunk = 0; chunk < 4; chunk++) {
        const float* src; int sstride;
        if (chunk == 0)      { src = x_sem + (size_t)base*512;       sstride = 512; }
        else if (chunk == 1) { src = x_sem + (size_t)base*512 + 256; sstride = 512; }
        else if (chunk == 2) { src = h_pos + (size_t)base*256;       sstride = 256; }
        else                 { src = h_aff + (size_t)base*256;       sstride = 256; }

        for (int i = tid; i < 64*64; i += 256) {
            int row = i >> 6, c4 = (i & 63) * 4;
            float4 v = {0.f, 0.f, 0.f, 0.f};
            if (row < nn) v = *(const float4*)&src[(size_t)row*sstride + c4];
            ushort4 h;
            h.x = f32_to_bf16_rne(v.x); h.y = f32_to_bf16_rne(v.y);
            h.z = f32_to_bf16_rne(v.z); h.w = f32_to_bf16_rne(v.w);
            *(ushort4*)&As[row*NA_STRIDE + c4] = h;
        }
        __syncthreads();

        #pragma unroll
        for (int kc = 0; kc < 8; kc++) {
            int k0 = kc*32 + lquad*8;
            short8 a[4], b[4];
            #pragma unroll
            for (int mi = 0; mi < 4; mi++)
                a[mi] = *(const short8*)&As[(mi*16 + lrow)*NA_STRIDE + k0];
            #pragma unroll
            for (int ni = 0; ni < 4; ni++)
                b[ni] = *(const short8*)&BtN[(size_t)(nbase + ni*16 + lrow)*1024
                                             + chunk*256 + k0];
            #pragma unroll
            for (int mi = 0; mi < 4; mi++)
                #pragma unroll
                for (int ni = 0; ni < 4; ni++)
                    acc[mi][ni] = __builtin_amdgcn_mfma_f32_16x16x32_bf16(
                                      a[mi], b[ni], acc[mi][ni], 0, 0, 0);
        }
        __syncthreads();
    }

    // epilogue: acc += const; LN stats from registers; direct store
    float cst[4], gcol[4], bcol[4];
    #pragma unroll
    for (int ni = 0; ni < 4; ni++) {
        int col = nbase + ni*16 + lrow;
        cst[ni] = node_const[col]; gcol[ni] = ln_g[col]; bcol[ni] = ln_b[col];
    }
    #pragma unroll
    for (int mi = 0; mi < 4; mi++)
        #pragma unroll
        for (int ni = 0; ni < 4; ni++)
            #pragma unroll
            for (int r = 0; r < 4; r++)
                acc[mi][ni][r] += cst[ni];

    #pragma unroll
    for (int mi = 0; mi < 4; mi++)
        #pragma unroll
        for (int r = 0; r < 4; r++) {
            float sv = acc[mi][0][r] + acc[mi][1][r] + acc[mi][2][r] + acc[mi][3][r];
            float qv = acc[mi][0][r]*acc[mi][0][r] + acc[mi][1][r]*acc[mi][1][r]
                     + acc[mi][2][r]*acc[mi][2][r] + acc[mi][3][r]*acc[mi][3][r];
            #pragma unroll
            for (int off = 1; off < 16; off <<= 1) {
                sv += __shfl_xor(sv, off, 64);
                qv += __shfl_xor(qv, off, 64);
            }
            if (lrow == 0) {
                int m = mi*16 + lquad*4 + r;
                rowred[wave][m][0] = sv;
                rowred[wave][m][1] = qv;
            }
        }
    __syncthreads();
    if (tid < 64) {
        float sv = rowred[0][tid][0] + rowred[1][tid][0] + rowred[2][tid][0] + rowred[3][tid][0];
        float qv = rowred[0][tid][1] + rowred[1][tid][1] + rowred[2][tid][1] + rowred[3][tid][1];
        float mean = sv * (1.f/256.f);
        mr[tid][0] = mean;
        mr[tid][1] = rsqrtf(qv * (1.f/256.f) - mean*mean + LN_EPS);
    }
    __syncthreads();

    #pragma unroll
    for (int mi = 0; mi < 4; mi++)
        #pragma unroll
        for (int r = 0; r < 4; r++) {
            int m = mi*16 + lquad*4 + r;
            if (m < nn) {
                float mean = mr[m][0], rstd = mr[m][1];
                #pragma unroll
                for (int ni = 0; ni < 4; ni++) {
                    float y = (acc[mi][ni][r] - mean) * rstd * gcol[ni] + bcol[ni];
                    out[(size_t)(base + m)*256 + nbase + ni*16 + lrow] = fmaxf(y, 0.f);
                }
            }
        }
}

// ---------------------------------------------------------------------------
// edge MFMA v2: same register-LN epilogue; h1tmp/rowred/mr share one scratch
// region. LDS ~50.6 KB -> 3 blocks/CU.
// ---------------------------------------------------------------------------
#define EA_STRIDE 328
#define H1_STRIDE 257

__global__ __launch_bounds__(256, 3) void edge_mfma_kernel(
    const int* __restrict__ etype, const float* __restrict__ eparam,
    const float* __restrict__ eanchor, const float* __restrict__ epose,
    const float* __restrict__ ep_W1, const float* __restrict__ ep_b1,
    const float* __restrict__ ep_ln_g, const float* __restrict__ ep_ln_b,
    const unsigned short* __restrict__ BtE,
    const float* __restrict__ type_proj, const float* __restrict__ edge_const,
    const float* __restrict__ ln_g, const float* __restrict__ ln_b,
    float* __restrict__ out, int E)
{
    __shared__ __align__(16) unsigned short As[64 * EA_STRIDE]; // 41984 B
    __shared__ __align__(16) float scr[8 * H1_STRIDE];          // 8224 B union
    __shared__ float va[64][5];
    __shared__ int   ty[64];
    __shared__ float mr8[8][2];

    float* h1tmp = scr;                 // h1 phase
    float* rowred = scr;                // epilogue: [wave*128 + m*2 + {0,1}]
    float* mrp = scr + 512;             // epilogue: [m*2 + {0,1}]

    int tid = threadIdx.x;
    int base = blockIdx.x * 64;
    int ne = min(64, E - base);

    for (int i = tid; i < 64*EA_STRIDE/4; i += 256)
        ((ushort4*)As)[i] = (ushort4){0, 0, 0, 0};
    if (tid < 64) {
        int e = tid;
        if (e < ne) {
            float d  = eparam[(size_t)(base+e)*3 + 0];
            float th = eparam[(size_t)(base+e)*3 + 1];
            float ph = eparam[(size_t)(base+e)*3 + 2];
            va[e][0] = fminf(fmaxf(d*10.f, -5.f), 5.f);
            va[e][1] = __sinf(th); va[e][2] = __cosf(th);
            va[e][3] = __sinf(ph); va[e][4] = __cosf(ph);
            ty[e] = etype[base+e];
        } else {
            va[e][0]=va[e][1]=va[e][2]=va[e][3]=va[e][4]=0.f; ty[e]=0;
        }
    }
    __syncthreads();

    for (int i = tid; i < 64*24; i += 256) {
        float v = (i < ne*24) ? eanchor[(size_t)base*24 + i] : 0.f;
        As[(i/24)*EA_STRIDE + 256 + (i % 24)] = f32_to_bf16_rne(v);
    }
    for (int i = tid; i < 64*9; i += 256) {
        float v = (i < ne*9) ? epose[(size_t)base*9 + i] : 0.f;
        As[(i/9)*EA_STRIDE + 280 + (i % 9)] = f32_to_bf16_rne(v);
    }

    int c = tid;
    float w0=ep_W1[c], w1=ep_W1[256+c], w2=ep_W1[512+c], w3=ep_W1[768+c], w4=ep_W1[1024+c];
    float bb = ep_b1[c];
    float gc1 = ep_ln_g[c], bc1 = ep_ln_b[c];
    for (int g = 0; g < 8; g++) {
        float t[8];
        #pragma unroll
        for (int e = 0; e < 8; e++) {
            int ge = g*8 + e;
            t[e] = va[ge][0]*w0 + va[ge][1]*w1 + va[ge][2]*w2 + va[ge][3]*w3
                 + va[ge][4]*w4 + bb;
            h1tmp[e*H1_STRIDE + c] = t[e];
        }
        __syncthreads();
        ln_reduce_rows2(h1tmp, H1_STRIDE, mr8, tid);
        __syncthreads();
        #pragma unroll
        for (int e = 0; e < 8; e++) {
            float y = fmaxf((t[e] - mr8[e][0]) * mr8[e][1] * gc1 + bc1, 0.f);
            As[(g*8 + e)*EA_STRIDE + c] = f32_to_bf16_rne(y);
        }
        __syncthreads();
    }

    int wave  = tid >> 6;
    int lane  = tid & 63;
    int lrow  = lane & 15;
    int lquad = lane >> 4;
    int nbase = wave * 64;

    floatx4 acc[4][4];
    #pragma unroll
    for (int mi = 0; mi < 4; mi++)
        #pragma unroll
        for (int ni = 0; ni < 4; ni++)
            acc[mi][ni] = (floatx4){0.f, 0.f, 0.f, 0.f};

    #pragma unroll
    for (int kc = 0; kc < 10; kc++) {
        int k0 = kc*32 + lquad*8;
        short8 a[4], b[4];
        #pragma unroll
        for (int mi = 0; mi < 4; mi++)
            a[mi] = *(const short8*)&As[(mi*16 + lrow)*EA_STRIDE + k0];
        #pragma unroll
        for (int ni = 0; ni < 4; ni++)
            b[ni] = *(const short8*)&BtE[(size_t)(nbase + ni*16 + lrow)*320 + k0];
        #pragma unroll
        for (int mi = 0; mi < 4; mi++)
            #pragma unroll
            for (int ni = 0; ni < 4; ni++)
                acc[mi][ni] = __builtin_amdgcn_mfma_f32_16x16x32_bf16(
                                  a[mi], b[ni], acc[mi][ni], 0, 0, 0);
    }
    __syncthreads();   // done with As/h1tmp; scr becomes rowred/mr

    // epilogue: acc += const + type_proj; LN from registers; direct store
    float cst[4], gcol[4], bcol[4];
    #pragma unroll
    for (int ni = 0; ni < 4; ni++) {
        int col = nbase + ni*16 + lrow;
        cst[ni] = edge_const[col]; gcol[ni] = ln_g[col]; bcol[ni] = ln_b[col];
    }
    #pragma unroll
    for (int mi = 0; mi < 4; mi++)
        #pragma unroll
        for (int r = 0; r < 4; r++) {
            int m = mi*16 + lquad*4 + r;
            const float* tpr = type_proj + ty[m]*256 + nbase;
            #pragma unroll
            for (int ni = 0; ni < 4; ni++)
                acc[mi][ni][r] += cst[ni] + tpr[ni*16 + lrow];
        }

    #pragma unroll
    for (int mi = 0; mi < 4; mi++)
        #pragma unroll
        for (int r = 0; r < 4; r++) {
            float sv = acc[mi][0][r] + acc[mi][1][r] + acc[mi][2][r] + acc[mi][3][r];
            float qv = acc[mi][0][r]*acc[mi][0][r] + acc[mi][1][r]*acc[mi][1][r]
                     + acc[mi][2][r]*acc[mi][2][r] + acc[mi][3][r]*acc[mi][3][r];
            #pragma unroll
            for (int off = 1; off < 16; off <<= 1) {
                sv += __shfl_xor(sv, off, 64);
                qv += __shfl_xor(qv, off, 64);
            }
            if (lrow == 0) {
                int m = mi*16 + lquad*4 + r;
                rowred[wave*128 + m*2 + 0] = sv;
                rowred[wave*128 + m*2 + 1] = qv;
            }
        }
    __syncthreads();
    if (tid < 64) {
        float sv = rowred[0*128 + tid*2] + rowred[1*128 + tid*2]
                 + rowred[2*128 + tid*2] + rowred[3*128 + tid*2];
        float qv = rowred[0*128 + tid*2+1] + rowred[1*128 + tid*2+1]
                 + rowred[2*128 + tid*2+1] + rowred[3*128 + tid*2+1];
        float mean = sv * (1.f/256.f);
        mrp[tid*2 + 0] = mean;
        mrp[tid*2 + 1] = rsqrtf(qv * (1.f/256.f) - mean*mean + LN_EPS);
    }
    __syncthreads();

    #pragma unroll
    for (int mi = 0; mi < 4; mi++)
        #pragma unroll
        for (int r = 0; r < 4; r++) {
            int m = mi*16 + lquad*4 + r;
            if (m < ne) {
                float mean = mrp[m*2 + 0], rstd = mrp[m*2 + 1];
                #pragma unroll
                for (int ni = 0; ni < 4; ni++) {
                    float y = (acc[mi][ni][r] - mean) * rstd * gcol[ni] + bcol[ni];
                    out[(size_t)(base + m)*256 + nbase + ni*16 + lrow] = fmaxf(y, 0.f);
                }
            }
        }
}

// ---------------------------------------------------------------------------
extern "C" void kernel_launch(void* const* d_in, const int* in_sizes, int n_in,
                              void* d_out, int out_size, void* d_ws, size_t ws_size,
                              hipStream_t stream)
{
    const float* x_sem     = (const float*)d_in[0];
    const float* x_pos     = (const float*)d_in[1];
    const int*   pos_bidx  = (const int*)  d_in[2];
    const float* x_aff     = (const float*)d_in[3];
    const int*   aff_bidx  = (const int*)  d_in[4];
    const int*   edge_type = (const int*)  d_in[5];
    const float* edge_param  = (const float*)d_in[6];
    const float* edge_anchor = (const float*)d_in[7];
    const float* edge_pose   = (const float*)d_in[8];
    const float* sem_W  = (const float*)d_in[10];
    const float* sem_b  = (const float*)d_in[11];
    const float* pos_W1 = (const float*)d_in[12];
    const float* pos_b1 = (const float*)d_in[13];
    const float* pos_bn_g = (const float*)d_in[14];
    const float* pos_bn_b = (const float*)d_in[15];
    const float* pos_W2 = (const float*)d_in[16];
    const float* pos_b2 = (const float*)d_in[17];
    const float* aff_W1 = (const float*)d_in[18];
    const float* aff_b1 = (const float*)d_in[19];
    const float* aff_bn_g = (const float*)d_in[20];
    const float* aff_bn_b = (const float*)d_in[21];
    const float* aff_W2 = (const float*)d_in[22];
    const float* aff_b2 = (const float*)d_in[23];
    const float* nf_W   = (const float*)d_in[24];
    const float* nf_b   = (const float*)d_in[25];
    const float* nf_ln_g = (const float*)d_in[26];
    const float* nf_ln_b = (const float*)d_in[27];
    const float* et_emb = (const float*)d_in[28];
    const float* ep_W1  = (const float*)d_in[29];
    const float* ep_b1  = (const float*)d_in[30];
    const float* ep_ln_g = (const float*)d_in[31];
    const float* ep_ln_b = (const float*)d_in[32];
    const float* ep_W2  = (const float*)d_in[33];
    const float* ep_b2  = (const float*)d_in[34];
    const float* ea_W   = (const float*)d_in[35];
    const float* ea_b   = (const float*)d_in[36];
    const float* epo_W  = (const float*)d_in[37];
    const float* epo_b  = (const float*)d_in[38];
    const float* ef_W   = (const float*)d_in[39];
    const float* ef_b   = (const float*)d_in[40];
    const float* ef_ln_g = (const float*)d_in[41];
    const float* ef_ln_b = (const float*)d_in[42];

    int N  = in_sizes[0] / 512;
    int Pp = in_sizes[1] / 3;
    int Pa = in_sizes[3] / 3;
    int E  = in_sizes[5];
    int N2 = (N + 4095) & ~4095;          // cnt arrays padded for int4 scan

    float* ws = (float*)d_ws;
    size_t off = 0;
    float* h_pos = ws + off;      off += (size_t)N*256;
    float* h_aff = ws + off;      off += (size_t)N*256;
    float* stats = ws + off;      off += 32;              // [0..15]=pos,[16..31]=aff
    int* cnt_pos = (int*)(ws+off); off += N2;
    int* cnt_aff = (int*)(ws+off); off += N2;
    int* base_pos = (int*)(ws+off); off += N;
    int* base_aff = (int*)(ws+off); off += N;
    off = (off + 3) & ~(size_t)3;                          // 16B align for float4
    float* xs_pos = ws + off;     off += (size_t)Pp*4;
    int* nd_pos = (int*)(ws+off); off += Pp;
    off = (off + 3) & ~(size_t)3;
    float* xs_aff = ws + off;     off += (size_t)Pa*4;
    int* nd_aff = (int*)(ws+off); off += Pa;
    off = (off + 3) & ~(size_t)3;
    float* W1f_all = ws + off;    off += 1536;            // pos 768 | aff 768
    float* b1f_all = ws + off;    off += 512;             // pos 256 | aff 256
    float* sem_comb   = ws + off; off += 512*256;
    float* param_comb = ws + off; off += 256*256;
    float* anchor_comb= ws + off; off += 24*256;
    float* pose_comb  = ws + off; off += 9*256;
    float* type_proj  = ws + off; off += 7*256;
    float* node_const = ws + off; off += 256;
    float* edge_const = ws + off; off += 256;
    unsigned short* Wt_all = (unsigned short*)(ws + off);  // pos 64K | aff 64K shorts
    unsigned short* BtN    = Wt_all + 2*65536;
    unsigned short* BtE    = BtN + 256*1024;

    // zero stats + padded CSR counters (contiguous region)
    (void)hipMemsetAsync(stats, 0, (32 + 2*(size_t)N2) * sizeof(int), stream);

    stats_kernel<<<1024, 256, 0, stream>>>(x_pos, Pp, x_aff, Pa, stats);
    count_kernel<<<1024, 256, 0, stream>>>(pos_bidx, aff_bidx, Pp, Pa, cnt_pos, cnt_aff);
    scan2_kernel<<<2, 1024, 0, stream>>>(cnt_pos, cnt_aff, base_pos, base_aff, N);
    scatter_kernel<<<1024, 256, 0, stream>>>(x_pos, pos_bidx, Pp, x_aff, aff_bidx, Pa,
                                             base_pos, base_aff,
                                             (float4*)xs_pos, nd_pos,
                                             (float4*)xs_aff, nd_aff);

    fold_bn_kernel<<<2, 256, 0, stream>>>(stats,
                                          pos_W1, pos_b1, pos_bn_g, pos_bn_b,
                                          aff_W1, aff_b1, aff_bn_g, aff_bn_b,
                                          1.f/(float)Pp, 1.f/(float)Pa,
                                          W1f_all, b1f_all);
    convert_w2_kernel<<<512, 256, 0, stream>>>(pos_W2, aff_W2, Wt_all);

    small_matmul_kernel<<<512, 256, 0, stream>>>(sem_W,  nf_W,            sem_comb,   256);
    small_matmul_kernel<<<256, 256, 0, stream>>>(ep_W2,  ef_W + 256*256,  param_comb, 256);
    small_matmul_kernel<<<24,  256, 0, stream>>>(ea_W,   ef_W + 512*256,  anchor_comb,256);
    small_matmul_kernel<<<9,   256, 0, stream>>>(epo_W,  ef_W + 768*256,  pose_comb,  256);
    small_matmul_kernel<<<7,   256, 0, stream>>>(et_emb, ef_W,            type_proj,  256);
    consts_kernel<<<1, 256, 0, stream>>>(sem_b, nf_W, nf_b, ep_b2, ea_b, epo_b, ef_W, ef_b,
                                         node_const, edge_const);
    convert_node_B<<<256, 256, 0, stream>>>(sem_comb, nf_W, BtN);
    convert_edge_B<<<256, 256, 0, stream>>>(param_comb, anchor_comb, pose_comb, BtE);

    // after scatter, base_* hold END offsets per node
    int nbPer = (N + 31) / 32;
    pce_seg_kernel<<<2*nbPer*4, 256, 0, stream>>>(xs_pos, nd_pos, base_pos,
                                                  xs_aff, nd_aff, base_aff,
                                                  W1f_all, b1f_all, Wt_all,
                                                  pos_b2, aff_b2,
                                                  h_pos, h_aff, N, nbPer);

    node_mfma_kernel<<<(N + 63)/64, 256, 0, stream>>>(x_sem, h_pos, h_aff, BtN, node_const,
                                                      nf_ln_g, nf_ln_b,
                                                      (float*)d_out, N);
    edge_mfma_kernel<<<(E + 63)/64, 256, 0, stream>>>(edge_type, edge_param, edge_anchor,
                                                      edge_pose, ep_W1, ep_b1,
                                                      ep_ln_g, ep_ln_b, BtE,
                                                      type_proj, edge_const,
                                                      ef_ln_g, ef_ln_b,
                                                      (float*)d_out + (size_t)N*256, E);
}

// Round 5
// 1498.417 us; speedup vs baseline: 1.8042x; 1.3488x over previous
//
#include <hip/hip_runtime.h>
#include <math.h>

#define LN_EPS 1e-5f

typedef __attribute__((ext_vector_type(8))) short short8;   // 8 bf16 = 4 VGPRs
typedef __attribute__((ext_vector_type(4))) float floatx4;  // MFMA C/D
typedef __attribute__((ext_vector_type(4))) int   intx4;

__device__ __forceinline__ unsigned short f32_to_bf16_rne(float v) {
    unsigned int u = __float_as_uint(v);
    return (unsigned short)((u + 0x7FFFu + ((u >> 16) & 1u)) >> 16);
}

// hardware packed cvt: dst = [bf16(hi) : bf16(lo)], RNE (T12: no builtin, asm)
__device__ __forceinline__ int cvt_pk_bf16(float lo, float hi) {
    int r;
    asm("v_cvt_pk_bf16_f32 %0, %1, %2" : "=v"(r) : "v"(lo), "v"(hi));
    return r;
}

// ---------------------------------------------------------------------------
// K1: stats + count fused (one pass over x and bidx, both encoders)
// ---------------------------------------------------------------------------
__global__ __launch_bounds__(256) void stats_count_kernel(
    const float* __restrict__ xp, const int* __restrict__ bp, int Pp,
    const float* __restrict__ xa, const int* __restrict__ ba, int Pa,
    float* __restrict__ stats, int* __restrict__ cnt_pos, int* __restrict__ cnt_aff) {
    int half = gridDim.x >> 1;
    bool aff = (int)blockIdx.x >= half;
    const float* x = aff ? xa : xp;
    const int* bidx = aff ? ba : bp;
    int P = aff ? Pa : Pp;
    float* st = stats + (aff ? 16 : 0);
    int* cnt = aff ? cnt_aff : cnt_pos;
    int b = aff ? blockIdx.x - half : blockIdx.x;
    int tid = b * 256 + threadIdx.x;
    int stride = half * 256;
    float s[9] = {0.f,0.f,0.f,0.f,0.f,0.f,0.f,0.f,0.f};
    for (int i = tid; i < P; i += stride) {
        float a = x[i*3+0], bb = x[i*3+1], c = x[i*3+2];
        atomicAdd(&cnt[bidx[i]], 1);
        s[0]+=a; s[1]+=bb; s[2]+=c;
        s[3]+=a*a; s[4]+=a*bb; s[5]+=a*c;
        s[6]+=bb*bb; s[7]+=bb*c; s[8]+=c*c;
    }
    #pragma unroll
    for (int j = 0; j < 9; j++) {
        float v = s[j];
        for (int off = 32; off > 0; off >>= 1) v += __shfl_down(v, off, 64);
        if ((threadIdx.x & 63) == 0) atomicAdd(&st[j], v);
    }
}

// exclusive scan, 1024 threads, int4 per thread (cnt padded to N2 with zeros)
__global__ __launch_bounds__(1024) void scan2_kernel(const int* __restrict__ cnt_pos,
                                                     const int* __restrict__ cnt_aff,
                                                     int* __restrict__ base_pos,
                                                     int* __restrict__ base_aff, int N) {
    const int* cnt = blockIdx.x ? cnt_aff : cnt_pos;
    int* base      = blockIdx.x ? base_aff : base_pos;
    __shared__ int wsum[16];
    __shared__ int carry;
    int tid = threadIdx.x, lane = tid & 63, wave = tid >> 6;
    if (tid == 0) carry = 0;
    __syncthreads();
    for (int t0 = 0; t0 < N; t0 += 4096) {
        int i4 = t0 + tid * 4;
        int4 v = *(const int4*)&cnt[i4];
        int tt = v.x + v.y + v.z + v.w;
        int s = tt;
        #pragma unroll
        for (int off = 1; off < 64; off <<= 1) {
            int u = __shfl_up(s, off, 64);
            if (lane >= off) s += u;
        }
        __syncthreads();
        if (lane == 63) wsum[wave] = s;
        __syncthreads();
        int c0 = carry;
        int woff = c0, tot = 0;
        #pragma unroll
        for (int w = 0; w < 16; w++) { int z = wsum[w]; tot += z; if (w < wave) woff += z; }
        int excl = woff + s - tt;
        if (i4     < N) base[i4]     = excl;
        if (i4 + 1 < N) base[i4 + 1] = excl + v.x;
        if (i4 + 2 < N) base[i4 + 2] = excl + v.x + v.y;
        if (i4 + 3 < N) base[i4 + 3] = excl + v.x + v.y + v.z;
        __syncthreads();
        if (tid == 0) carry = c0 + tot;
    }
}

// scatter: pos = base[n]++; xsort[pos] = {x,y,z,0}; ndsort[pos] = n.
__global__ __launch_bounds__(256) void scatter_kernel(
    const float* __restrict__ xp, const int* __restrict__ bp, int Pp,
    const float* __restrict__ xa, const int* __restrict__ ba, int Pa,
    int* __restrict__ base_pos, int* __restrict__ base_aff,
    float4* __restrict__ xs_pos, int* __restrict__ nd_pos,
    float4* __restrict__ xs_aff, int* __restrict__ nd_aff) {
    int half = gridDim.x >> 1;
    bool isAff = (int)blockIdx.x >= half;
    const float* x  = isAff ? xa : xp;
    const int* bidx = isAff ? ba : bp;
    int P           = isAff ? Pa : Pp;
    int* base       = isAff ? base_aff : base_pos;
    float4* xs      = isAff ? xs_aff : xs_pos;
    int* nd         = isAff ? nd_aff : nd_pos;
    int b = isAff ? blockIdx.x - half : blockIdx.x;
    int stride = half * 256;
    for (int i = b*256 + threadIdx.x; i < P; i += stride) {
        int n = bidx[i];
        int pos = atomicAdd(&base[n], 1);
        float4 v;
        v.x = x[i*3+0]; v.y = x[i*3+1]; v.z = x[i*3+2]; v.w = 0.f;
        xs[pos] = v;
        nd[pos] = n;
    }
}

// ---------------------------------------------------------------------------
// K4: mega prep — all weight folds/transposes/small matmuls/consts in ONE
// launch. Matmul sections write the bf16-TRANSPOSED B matrices directly
// (sem_comb/param_comb/... never materialized).
// Sections (grid = 1837):
//   [0,512)    sem:    BtN[c*1024 + r]     = bf16( sem_W[r]   @ nf_W[0:256]  )
//   [512,768)  param:  BtE[c*320 + r]      = bf16( ep_W2[r]   @ ef_W[256:512])
//   [768,792)  anchor: BtE[c*320 + 256+r]  = bf16( ea_W[r]    @ ef_W[512:768])
//   [792,801)  pose:   BtE[c*320 + 280+r]  = bf16( epo_W[r]   @ ef_W[768:1024])
//   [801,808)  type_proj[r*256+c] (fp32)   =       et_emb[r]  @ ef_W[0:256]
//   [808,810)  consts (node / edge)
//   [810,812)  fold_bn (pos / aff)
//   [812,1324) convert W2 -> Wt_all (bf16 transposed)
//   [1324,1836) BtN[c*1024 + 512+b] = bf16(nf_W[(256+b)*256 + c])
//   [1836]     BtE pad cols 289..319 = 0
// ---------------------------------------------------------------------------
__global__ __launch_bounds__(256) void prep_mega(
    const float* __restrict__ sem_W,  const float* __restrict__ nf_W,
    const float* __restrict__ ep_W2,  const float* __restrict__ ef_W,
    const float* __restrict__ ea_W,   const float* __restrict__ epo_W,
    const float* __restrict__ et_emb,
    const float* __restrict__ sem_b,  const float* __restrict__ nf_b,
    const float* __restrict__ ep_b2,  const float* __restrict__ ea_b,
    const float* __restrict__ epo_b,  const float* __restrict__ ef_b,
    const float* __restrict__ stats,
    const float* __restrict__ pos_W1, const float* __restrict__ pos_b1,
    const float* __restrict__ pos_bn_g, const float* __restrict__ pos_bn_b,
    const float* __restrict__ aff_W1, const float* __restrict__ aff_b1,
    const float* __restrict__ aff_bn_g, const float* __restrict__ aff_bn_b,
    float Pinv_p, float Pinv_a,
    const float* __restrict__ pos_W2, const float* __restrict__ aff_W2,
    unsigned short* __restrict__ BtN, unsigned short* __restrict__ BtE,
    float* __restrict__ type_proj,
    float* __restrict__ node_const, float* __restrict__ edge_const,
    float* __restrict__ W1f_all, float* __restrict__ b1f_all,
    unsigned short* __restrict__ Wt_all)
{
    int b = blockIdx.x, c = threadIdx.x;

    if (b < 512) {                                    // sem
        const float* Ar = sem_W + (size_t)b * 256;
        float acc = 0.f;
        for (int j = 0; j < 256; j++) acc += Ar[j] * nf_W[j*256 + c];
        BtN[(size_t)c*1024 + b] = f32_to_bf16_rne(acc);
        return;
    }
    b -= 512;
    if (b < 256) {                                    // param
        const float* Ar = ep_W2 + (size_t)b * 256;
        const float* B = ef_W + 256*256;
        float acc = 0.f;
        for (int j = 0; j < 256; j++) acc += Ar[j] * B[j*256 + c];
        BtE[(size_t)c*320 + b] = f32_to_bf16_rne(acc);
        return;
    }
    b -= 256;
    if (b < 24) {                                     // anchor
        const float* Ar = ea_W + (size_t)b * 256;
        const float* B = ef_W + 512*256;
        float acc = 0.f;
        for (int j = 0; j < 256; j++) acc += Ar[j] * B[j*256 + c];
        BtE[(size_t)c*320 + 256 + b] = f32_to_bf16_rne(acc);
        return;
    }
    b -= 24;
    if (b < 9) {                                      // pose
        const float* Ar = epo_W + (size_t)b * 256;
        const float* B = ef_W + 768*256;
        float acc = 0.f;
        for (int j = 0; j < 256; j++) acc += Ar[j] * B[j*256 + c];
        BtE[(size_t)c*320 + 280 + b] = f32_to_bf16_rne(acc);
        return;
    }
    b -= 9;
    if (b < 7) {                                      // type_proj (fp32)
        const float* Ar = et_emb + (size_t)b * 256;
        float acc = 0.f;
        for (int j = 0; j < 256; j++) acc += Ar[j] * ef_W[j*256 + c];
        type_proj[b*256 + c] = acc;
        return;
    }
    b -= 7;
    if (b < 2) {                                      // consts
        if (b == 0) {
            float nc = nf_b[c];
            for (int j = 0; j < 256; j++) nc += sem_b[j] * nf_W[j*256 + c];
            node_const[c] = nc;
        } else {
            float ec = ef_b[c];
            for (int j = 0; j < 256; j++) ec += ep_b2[j] * ef_W[(256+j)*256 + c];
            for (int j = 0; j < 24;  j++) ec += ea_b[j]  * ef_W[(512+j)*256 + c];
            for (int j = 0; j < 9;   j++) ec += epo_b[j] * ef_W[(768+j)*256 + c];
            edge_const[c] = ec;
        }
        return;
    }
    b -= 2;
    if (b < 2) {                                      // fold_bn
        int sel = b;
        const float* st = stats + sel*16;
        const float* W1 = sel ? aff_W1 : pos_W1;
        const float* b1 = sel ? aff_b1 : pos_b1;
        const float* g  = sel ? aff_bn_g : pos_bn_g;
        const float* bg = sel ? aff_bn_b : pos_bn_b;
        float Pinv = sel ? Pinv_a : Pinv_p;
        float* W1f = W1f_all + sel*768;
        float* b1f = b1f_all + sel*256;
        float m0 = st[0]*Pinv, m1 = st[1]*Pinv, m2 = st[2]*Pinv;
        float C00 = st[3]*Pinv - m0*m0;
        float C01 = st[4]*Pinv - m0*m1;
        float C02 = st[5]*Pinv - m0*m2;
        float C11 = st[6]*Pinv - m1*m1;
        float C12 = st[7]*Pinv - m1*m2;
        float C22 = st[8]*Pinv - m2*m2;
        float w0 = W1[c], w1 = W1[256+c], w2 = W1[512+c];
        float mean = m0*w0 + m1*w1 + m2*w2 + b1[c];
        float var  = C00*w0*w0 + C11*w1*w1 + C22*w2*w2
                   + 2.f*(C01*w0*w1 + C02*w0*w2 + C12*w1*w2);
        float a = g[c] * rsqrtf(var + LN_EPS);
        W1f[c]     = w0*a;
        W1f[256+c] = w1*a;
        W1f[512+c] = w2*a;
        b1f[c] = (b1[c] - mean)*a + bg[c];
        return;
    }
    b -= 2;
    if (b < 512) {                                    // convert W2
        int sel = b >> 8, n = b & 255;
        const float* W = sel ? aff_W2 : pos_W2;
        Wt_all[sel*65536 + n*256 + c] = f32_to_bf16_rne(W[c*256 + n]);
        return;
    }
    b -= 512;
    if (b < 512) {                                    // BtN hi cols (nf_W direct)
        BtN[(size_t)c*1024 + 512 + b] = f32_to_bf16_rne(nf_W[(size_t)(256+b)*256 + c]);
        return;
    }
    // BtE pad: cols 289..319 = 0
    for (int i = c; i < 256*32; i += 256) {
        int n = i >> 5, cc = 288 + (i & 31);
        if (cc > 288) BtE[(size_t)n*320 + cc] = 0;
    }
}

// ---------------------------------------------------------------------------
// point-cloud encoder v5: v4 structure (B-slice in swizzled LDS, col-split 4,
// M-split waves) + hardware v_cvt_pk_bf16_f32 in layer-1 (1 instr vs ~9-op
// RNE bit math) + bf16 seg output (direct handoff to node_mfma).
// ---------------------------------------------------------------------------
#define SEGA_STRIDE 66

__global__ __launch_bounds__(256, 3) void pce_seg_kernel(
    const float* __restrict__ xs_pos, const int* __restrict__ nd_pos,
    const int* __restrict__ be_pos,
    const float* __restrict__ xs_aff, const int* __restrict__ nd_aff,
    const int* __restrict__ be_aff,
    const float* __restrict__ W1f_all, const float* __restrict__ b1f_all,
    const unsigned short* __restrict__ Wt_all,
    const float* __restrict__ b2_pos, const float* __restrict__ b2_aff,
    unsigned short* __restrict__ seg_pos, unsigned short* __restrict__ seg_aff,
    int N, int nbPer)
{
    __shared__ __align__(16) short Bs[64 * 256];            // 32 KB swizzled
    __shared__ unsigned int segacc[32 * SEGA_STRIDE];       // 8448 B
    __shared__ __align__(16) float wk[256 * 4];             // 4 KB swizzled
    __shared__ float xsb[2][64 * 4];                        // 2 KB
    __shared__ int   ndb[2][64];                            // 512 B

    int tid = threadIdx.x;

    // bijective XCD swizzle (m204): consecutive logical blocks share an XCD
    int nwg = gridDim.x;
    int q8 = nwg >> 3, r8 = nwg & 7;
    int xcd = blockIdx.x & 7, loc = blockIdx.x >> 3;
    int wgid = (xcd < r8 ? xcd*(q8+1) : r8*(q8+1) + (xcd - r8)*q8) + loc;

    int per = nbPer * 4;
    bool isAff = wgid >= per;
    int rem = isAff ? wgid - per : wgid;
    int blk = rem >> 2;
    int colbase = (rem & 3) * 64;

    const float* xsf = isAff ? xs_aff : xs_pos;
    const int*   nds = isAff ? nd_aff : nd_pos;
    const int*   be  = isAff ? be_aff : be_pos;
    const unsigned short* Wt = Wt_all + (isAff ? 65536 : 0) + colbase*256;
    const float* b2  = isAff ? b2_aff : b2_pos;
    unsigned short* seg = isAff ? seg_aff : seg_pos;

    int n0 = blk * 32;
    int nlast = min(n0 + 32, N) - 1;
    int s = (n0 == 0) ? 0 : be[n0 - 1];
    int e = be[nlast];

    for (int i = tid; i < 32 * SEGA_STRIDE; i += 256) segacc[i] = 0u;
    {
        const float* W1f = W1f_all + (isAff ? 768 : 0);
        const float* b1f = b1f_all + (isAff ? 256 : 0);
        float4 w = make_float4(W1f[tid], W1f[256 + tid], W1f[512 + tid], b1f[tid]);
        *(float4*)&wk[(tid * 4) ^ ((tid & 24) >> 1)] = w;   // bank-spread per lquad
    }
    // stage B-slice once: 64 cols x 256 k, XOR-swizzle ((col&7)<<3 shorts)
    #pragma unroll
    for (int i = 0; i < 8; i++) {
        int j = i * 256 + tid;                 // 2048 short8 groups
        int col = j >> 5, k8 = (j & 31) << 3;
        short8 v = *(const short8*)&Wt[col * 256 + k8];
        *(short8*)&Bs[(col * 256 + k8) ^ ((col & 7) << 3)] = v;
    }

    int wave = tid >> 6, lane = tid & 63, lrow = lane & 15, lquad = lane >> 4;
    int pbase = wave * 16;
    float bias[4];
    #pragma unroll
    for (int ni = 0; ni < 4; ni++) bias[ni] = b2[colbase + ni*16 + lrow];

    // stage tile 0
    {
        float rx = 0.f; int rn = -1;
        int p = s + (tid >> 2);
        if (p < e) rx = xsf[(size_t)p * 4 + (tid & 3)];
        if (tid < 64) { int qq = s + tid; if (qq < e) rn = nds[qq] - n0; }
        xsb[0][tid] = rx;
        if (tid < 64) ndb[0][tid] = rn;
    }

    int buf = 0;
    for (int ts = s; ts < e; ts += 64, buf ^= 1) {
        // issue next-tile loads early
        float rx = 0.f; int rn = -1;
        int ts2 = ts + 64;
        if (ts2 < e) {
            int p = ts2 + (tid >> 2);
            if (p < e) rx = xsf[(size_t)p * 4 + (tid & 3)];
            if (tid < 64) { int qq = ts2 + tid; if (qq < e) rn = nds[qq] - n0; }
        }
        __syncthreads();   // tile buf staged (incl. B/wk on first iter)

        float4 pt = *(const float4*)&xsb[buf][(pbase + lrow) * 4];  // broadcast
        int nd4[4];
        #pragma unroll
        for (int r = 0; r < 4; r++) nd4[r] = ndb[buf][pbase + lquad*4 + r];

        floatx4 acc[4];
        #pragma unroll
        for (int ni = 0; ni < 4; ni++) acc[ni] = (floatx4){0.f, 0.f, 0.f, 0.f};

        #pragma unroll
        for (int kc = 0; kc < 8; kc++) {
            int kb = kc*32 + lquad*8;
            short8 bfr[4];
            #pragma unroll
            for (int ni = 0; ni < 4; ni++) {
                int c = ni*16 + lrow;
                bfr[ni] = *(const short8*)&Bs[(c*256 + kb) ^ ((c & 7) << 3)];
            }
            int af[4];
            #pragma unroll
            for (int j2 = 0; j2 < 4; j2++) {
                int c0 = kb + 2*j2, c1 = c0 + 1;
                float4 wA = *(const float4*)&wk[(c0*4) ^ ((c0 & 24) >> 1)];
                float4 wB = *(const float4*)&wk[(c1*4) ^ ((c1 & 24) >> 1)];
                float v0 = fmaxf(fmaf(pt.x, wA.x, fmaf(pt.y, wA.y, fmaf(pt.z, wA.z, wA.w))), 0.f);
                float v1 = fmaxf(fmaf(pt.x, wB.x, fmaf(pt.y, wB.y, fmaf(pt.z, wB.z, wB.w))), 0.f);
                af[j2] = cvt_pk_bf16(v0, v1);
            }
            short8 a = __builtin_bit_cast(short8, (intx4){af[0], af[1], af[2], af[3]});
            #pragma unroll
            for (int ni = 0; ni < 4; ni++)
                acc[ni] = __builtin_amdgcn_mfma_f32_16x16x32_bf16(a, bfr[ni], acc[ni], 0, 0, 0);
        }

        // write-late: stage next tile into other buffer
        xsb[buf ^ 1][tid] = rx;
        if (tid < 64) ndb[buf ^ 1][tid] = rn;

        // epilogue: relu(acc+bias) -> LDS segment max (run-dedupe, sorted rows)
        #pragma unroll
        for (int ni = 0; ni < 4; ni++) {
            int colloc = ni*16 + lrow;
            int cn = -1; float best = 0.f;
            #pragma unroll
            for (int r = 0; r < 4; r++) {
                float y = fmaxf(acc[ni][r] + bias[ni], 0.f);
                if (nd4[r] != cn) {
                    if (cn >= 0)
                        atomicMax(&segacc[cn*SEGA_STRIDE + colloc], __float_as_uint(best));
                    cn = nd4[r]; best = y;
                } else {
                    best = fmaxf(best, y);
                }
            }
            if (cn >= 0)
                atomicMax(&segacc[cn*SEGA_STRIDE + colloc], __float_as_uint(best));
        }
    }

    __syncthreads();
    for (int i = tid; i < 32 * 64; i += 256) {
        int t = i >> 6, c = i & 63;
        int n = n0 + t;
        if (n <= nlast)
            seg[(size_t)n*256 + colbase + c] =
                f32_to_bf16_rne(__uint_as_float(segacc[t*SEGA_STRIDE + c]));
    }
}

// ---------------------------------------------------------------------------
// node MFMA v3: h_pos/h_aff arrive as bf16 (raw 16B copy staging, no cvt);
// x_sem chunks use hardware cvt_pk. Register-LN epilogue (round 4).
// ---------------------------------------------------------------------------
#define NA_STRIDE 264

__global__ __launch_bounds__(256, 3) void node_mfma_kernel(
    const float* __restrict__ x_sem,
    const unsigned short* __restrict__ h_pos, const unsigned short* __restrict__ h_aff,
    const unsigned short* __restrict__ BtN,
    const float* __restrict__ node_const,
    const float* __restrict__ ln_g, const float* __restrict__ ln_b,
    float* __restrict__ out, int N)
{
    __shared__ __align__(16) unsigned short As[64 * NA_STRIDE];  // 33792 B
    __shared__ float rowred[4][64][2];                           // 2048 B
    __shared__ float mr[64][2];                                  // 512 B

    int tid = threadIdx.x;
    int base = blockIdx.x * 64;
    int nn = min(64, N - base);

    int wave  = tid >> 6;
    int lane  = tid & 63;
    int lrow  = lane & 15;
    int lquad = lane >> 4;
    int nbase = wave * 64;

    floatx4 acc[4][4];
    #pragma unroll
    for (int mi = 0; mi < 4; mi++)
        #pragma unroll
        for (int ni = 0; ni < 4; ni++)
            acc[mi][ni] = (floatx4){0.f, 0.f, 0.f, 0.f};

    #pragma unroll
    for (int chunk = 0; chunk < 4; chunk++) {
        if (chunk < 2) {
            const float* src = x_sem + (size_t)base*512 + chunk*256;
            for (int i = tid; i < 4096; i += 256) {
                int row = i >> 6, c4 = (i & 63) * 4;
                float4 v = {0.f, 0.f, 0.f, 0.f};
                if (row < nn) v = *(const float4*)&src[(size_t)row*512 + c4];
                int2 p;
                p.x = cvt_pk_bf16(v.x, v.y);
                p.y = cvt_pk_bf16(v.z, v.w);
                *(int2*)&As[row*NA_STRIDE + c4] = p;
            }
        } else {
            const unsigned short* src = (chunk == 2 ? h_pos : h_aff) + (size_t)base*256;
            for (int i = tid; i < 2048; i += 256) {
                int row = i >> 5, k8 = (i & 31) * 8;
                short8 v = (short8){0,0,0,0,0,0,0,0};
                if (row < nn) v = *(const short8*)&src[(size_t)row*256 + k8];
                *(short8*)&As[row*NA_STRIDE + k8] = v;
            }
        }
        __syncthreads();

        #pragma unroll
        for (int kc = 0; kc < 8; kc++) {
            int k0 = kc*32 + lquad*8;
            short8 a[4], b[4];
            #pragma unroll
            for (int mi = 0; mi < 4; mi++)
                a[mi] = *(const short8*)&As[(mi*16 + lrow)*NA_STRIDE + k0];
            #pragma unroll
            for (int ni = 0; ni < 4; ni++)
                b[ni] = *(const short8*)&BtN[(size_t)(nbase + ni*16 + lrow)*1024
                                             + chunk*256 + k0];
            #pragma unroll
            for (int mi = 0; mi < 4; mi++)
                #pragma unroll
                for (int ni = 0; ni < 4; ni++)
                    acc[mi][ni] = __builtin_amdgcn_mfma_f32_16x16x32_bf16(
                                      a[mi], b[ni], acc[mi][ni], 0, 0, 0);
        }
        __syncthreads();
    }

    // epilogue: acc += const; LN stats from registers; direct store
    float cst[4], gcol[4], bcol[4];
    #pragma unroll
    for (int ni = 0; ni < 4; ni++) {
        int col = nbase + ni*16 + lrow;
        cst[ni] = node_const[col]; gcol[ni] = ln_g[col]; bcol[ni] = ln_b[col];
    }
    #pragma unroll
    for (int mi = 0; mi < 4; mi++)
        #pragma unroll
        for (int ni = 0; ni < 4; ni++)
            #pragma unroll
            for (int r = 0; r < 4; r++)
                acc[mi][ni][r] += cst[ni];

    #pragma unroll
    for (int mi = 0; mi < 4; mi++)
        #pragma unroll
        for (int r = 0; r < 4; r++) {
            float sv = acc[mi][0][r] + acc[mi][1][r] + acc[mi][2][r] + acc[mi][3][r];
            float qv = acc[mi][0][r]*acc[mi][0][r] + acc[mi][1][r]*acc[mi][1][r]
                     + acc[mi][2][r]*acc[mi][2][r] + acc[mi][3][r]*acc[mi][3][r];
            #pragma unroll
            for (int off = 1; off < 16; off <<= 1) {
                sv += __shfl_xor(sv, off, 64);
                qv += __shfl_xor(qv, off, 64);
            }
            if (lrow == 0) {
                int m = mi*16 + lquad*4 + r;
                rowred[wave][m][0] = sv;
                rowred[wave][m][1] = qv;
            }
        }
    __syncthreads();
    if (tid < 64) {
        float sv = rowred[0][tid][0] + rowred[1][tid][0] + rowred[2][tid][0] + rowred[3][tid][0];
        float qv = rowred[0][tid][1] + rowred[1][tid][1] + rowred[2][tid][1] + rowred[3][tid][1];
        float mean = sv * (1.f/256.f);
        mr[tid][0] = mean;
        mr[tid][1] = rsqrtf(qv * (1.f/256.f) - mean*mean + LN_EPS);
    }
    __syncthreads();

    #pragma unroll
    for (int mi = 0; mi < 4; mi++)
        #pragma unroll
        for (int r = 0; r < 4; r++) {
            int m = mi*16 + lquad*4 + r;
            if (m < nn) {
                float mean = mr[m][0], rstd = mr[m][1];
                #pragma unroll
                for (int ni = 0; ni < 4; ni++) {
                    float y = (acc[mi][ni][r] - mean) * rstd * gcol[ni] + bcol[ni];
                    __builtin_nontemporal_store(fmaxf(y, 0.f),
                        &out[(size_t)(base + m)*256 + nbase + ni*16 + lrow]);
                }
            }
        }
}

// ---------------------------------------------------------------------------
// edge MFMA v3: h1 phase rewritten barrier-free — each wave owns 16 rows,
// lane owns 4 cols, full-row LN via shfl_xor (1 barrier vs 24). cvt_pk packs.
// Register-LN final epilogue (round 4).
// ---------------------------------------------------------------------------
#define EA_STRIDE 328

__global__ __launch_bounds__(256, 3) void edge_mfma_kernel(
    const int* __restrict__ etype, const float* __restrict__ eparam,
    const float* __restrict__ eanchor, const float* __restrict__ epose,
    const float* __restrict__ ep_W1, const float* __restrict__ ep_b1,
    const float* __restrict__ ep_ln_g, const float* __restrict__ ep_ln_b,
    const unsigned short* __restrict__ BtE,
    const float* __restrict__ type_proj, const float* __restrict__ edge_const,
    const float* __restrict__ ln_g, const float* __restrict__ ln_b,
    float* __restrict__ out, int E)
{
    __shared__ __align__(16) unsigned short As[64 * EA_STRIDE]; // 41984 B
    __shared__ float scr[640];                                  // rowred 512 | mr 128
    __shared__ float va[64][5];
    __shared__ int   ty[64];

    int tid = threadIdx.x;
    int base = blockIdx.x * 64;
    int ne = min(64, E - base);

    int lane = tid & 63, wave = tid >> 6;

    // pad cols 289..319 = 0 (h1 fills 0..255, anchor 256..279, pose 280..288)
    for (int i = tid; i < 64*32; i += 256) {
        int row = i >> 5, cc = 288 + (i & 31);
        if (cc > 288) As[row*EA_STRIDE + cc] = 0;
    }
    if (tid < 64) {
        int e = tid;
        if (e < ne) {
            float d  = eparam[(size_t)(base+e)*3 + 0];
            float th = eparam[(size_t)(base+e)*3 + 1];
            float ph = eparam[(size_t)(base+e)*3 + 2];
            va[e][0] = fminf(fmaxf(d*10.f, -5.f), 5.f);
            va[e][1] = __sinf(th); va[e][2] = __cosf(th);
            va[e][3] = __sinf(ph); va[e][4] = __cosf(ph);
            ty[e] = etype[base+e];
        } else {
            va[e][0]=va[e][1]=va[e][2]=va[e][3]=va[e][4]=0.f; ty[e]=0;
        }
    }
    __syncthreads();   // va visible to all waves

    // anchor/pose into A cols 256..288 (all 64 rows, zero-padded past ne)
    for (int i = tid; i < 64*24; i += 256) {
        float v = (i < ne*24) ? eanchor[(size_t)base*24 + i] : 0.f;
        As[(i/24)*EA_STRIDE + 256 + (i % 24)] = f32_to_bf16_rne(v);
    }
    for (int i = tid; i < 64*9; i += 256) {
        float v = (i < ne*9) ? epose[(size_t)base*9 + i] : 0.f;
        As[(i/9)*EA_STRIDE + 280 + (i % 9)] = f32_to_bf16_rne(v);
    }

    // h1: wave handles rows wave*16..+15; lane owns cols 4*lane..4*lane+3.
    // Row LN entirely via shfl_xor — no barriers, no LDS ping-pong.
    {
        int c4 = lane * 4;
        float4 Wr0 = *(const float4*)&ep_W1[0*256 + c4];
        float4 Wr1 = *(const float4*)&ep_W1[1*256 + c4];
        float4 Wr2 = *(const float4*)&ep_W1[2*256 + c4];
        float4 Wr3 = *(const float4*)&ep_W1[3*256 + c4];
        float4 Wr4 = *(const float4*)&ep_W1[4*256 + c4];
        float4 b1v = *(const float4*)&ep_b1[c4];
        float4 gv  = *(const float4*)&ep_ln_g[c4];
        float4 bv  = *(const float4*)&ep_ln_b[c4];
        #pragma unroll 4
        for (int t = 0; t < 16; t++) {
            int m = wave*16 + t;
            float v0 = va[m][0], v1 = va[m][1], v2 = va[m][2], v3 = va[m][3], v4 = va[m][4];
            float t0 = fmaf(v0,Wr0.x, fmaf(v1,Wr1.x, fmaf(v2,Wr2.x, fmaf(v3,Wr3.x, fmaf(v4,Wr4.x, b1v.x)))));
            float t1 = fmaf(v0,Wr0.y, fmaf(v1,Wr1.y, fmaf(v2,Wr2.y, fmaf(v3,Wr3.y, fmaf(v4,Wr4.y, b1v.y)))));
            float t2 = fmaf(v0,Wr0.z, fmaf(v1,Wr1.z, fmaf(v2,Wr2.z, fmaf(v3,Wr3.z, fmaf(v4,Wr4.z, b1v.z)))));
            float t3 = fmaf(v0,Wr0.w, fmaf(v1,Wr1.w, fmaf(v2,Wr2.w, fmaf(v3,Wr3.w, fmaf(v4,Wr4.w, b1v.w)))));
            float s = t0 + t1 + t2 + t3;
            float q = t0*t0 + t1*t1 + t2*t2 + t3*t3;
            #pragma unroll
            for (int off = 1; off < 64; off <<= 1) {
                s += __shfl_xor(s, off, 64);
                q += __shfl_xor(q, off, 64);
            }
            float mean = s * (1.f/256.f);
            float rstd = rsqrtf(q * (1.f/256.f) - mean*mean + LN_EPS);
            float y0 = fmaxf((t0 - mean) * rstd * gv.x + bv.x, 0.f);
            float y1 = fmaxf((t1 - mean) * rstd * gv.y + bv.y, 0.f);
            float y2 = fmaxf((t2 - mean) * rstd * gv.z + bv.z, 0.f);
            float y3 = fmaxf((t3 - mean) * rstd * gv.w + bv.w, 0.f);
            int2 p;
            p.x = cvt_pk_bf16(y0, y1);
            p.y = cvt_pk_bf16(y2, y3);
            *(int2*)&As[m*EA_STRIDE + c4] = p;
        }
    }
    __syncthreads();   // all As writes visible

    int lrow  = lane & 15;
    int lquad = lane >> 4;
    int nbase = wave * 64;

    floatx4 acc[4][4];
    #pragma unroll
    for (int mi = 0; mi < 4; mi++)
        #pragma unroll
        for (int ni = 0; ni < 4; ni++)
            acc[mi][ni] = (floatx4){0.f, 0.f, 0.f, 0.f};

    #pragma unroll
    for (int kc = 0; kc < 10; kc++) {
        int k0 = kc*32 + lquad*8;
        short8 a[4], b[4];
        #pragma unroll
        for (int mi = 0; mi < 4; mi++)
            a[mi] = *(const short8*)&As[(mi*16 + lrow)*EA_STRIDE + k0];
        #pragma unroll
        for (int ni = 0; ni < 4; ni++)
            b[ni] = *(const short8*)&BtE[(size_t)(nbase + ni*16 + lrow)*320 + k0];
        #pragma unroll
        for (int mi = 0; mi < 4; mi++)
            #pragma unroll
            for (int ni = 0; ni < 4; ni++)
                acc[mi][ni] = __builtin_amdgcn_mfma_f32_16x16x32_bf16(
                                  a[mi], b[ni], acc[mi][ni], 0, 0, 0);
    }

    // epilogue: acc += const + type_proj; LN from registers; direct store
    float* rowred = scr;          // [wave*128 + m*2 + {0,1}]
    float* mrp = scr + 512;       // [m*2 + {0,1}]
    float cst[4], gcol[4], bcol[4];
    #pragma unroll
    for (int ni = 0; ni < 4; ni++) {
        int col = nbase + ni*16 + lrow;
        cst[ni] = edge_const[col]; gcol[ni] = ln_g[col]; bcol[ni] = ln_b[col];
    }
    #pragma unroll
    for (int mi = 0; mi < 4; mi++)
        #pragma unroll
        for (int r = 0; r < 4; r++) {
            int m = mi*16 + lquad*4 + r;
            const float* tpr = type_proj + ty[m]*256 + nbase;
            #pragma unroll
            for (int ni = 0; ni < 4; ni++)
                acc[mi][ni][r] += cst[ni] + tpr[ni*16 + lrow];
        }

    #pragma unroll
    for (int mi = 0; mi < 4; mi++)
        #pragma unroll
        for (int r = 0; r < 4; r++) {
            float sv = acc[mi][0][r] + acc[mi][1][r] + acc[mi][2][r] + acc[mi][3][r];
            float qv = acc[mi][0][r]*acc[mi][0][r] + acc[mi][1][r]*acc[mi][1][r]
                     + acc[mi][2][r]*acc[mi][2][r] + acc[mi][3][r]*acc[mi][3][r];
            #pragma unroll
            for (int off = 1; off < 16; off <<= 1) {
                sv += __shfl_xor(sv, off, 64);
                qv += __shfl_xor(qv, off, 64);
            }
            if (lrow == 0) {
                int m = mi*16 + lquad*4 + r;
                rowred[wave*128 + m*2 + 0] = sv;
                rowred[wave*128 + m*2 + 1] = qv;
            }
        }
    __syncthreads();
    if (tid < 64) {
        float sv = rowred[0*128 + tid*2] + rowred[1*128 + tid*2]
                 + rowred[2*128 + tid*2] + rowred[3*128 + tid*2];
        float qv = rowred[0*128 + tid*2+1] + rowred[1*128 + tid*2+1]
                 + rowred[2*128 + tid*2+1] + rowred[3*128 + tid*2+1];
        float mean = sv * (1.f/256.f);
        mrp[tid*2 + 0] = mean;
        mrp[tid*2 + 1] = rsqrtf(qv * (1.f/256.f) - mean*mean + LN_EPS);
    }
    __syncthreads();

    #pragma unroll
    for (int mi = 0; mi < 4; mi++)
        #pragma unroll
        for (int r = 0; r < 4; r++) {
            int m = mi*16 + lquad*4 + r;
            if (m < ne) {
                float mean = mrp[m*2 + 0], rstd = mrp[m*2 + 1];
                #pragma unroll
                for (int ni = 0; ni < 4; ni++) {
                    float y = (acc[mi][ni][r] - mean) * rstd * gcol[ni] + bcol[ni];
                    __builtin_nontemporal_store(fmaxf(y, 0.f),
                        &out[(size_t)(base + m)*256 + nbase + ni*16 + lrow]);
                }
            }
        }
}

// ---------------------------------------------------------------------------
extern "C" void kernel_launch(void* const* d_in, const int* in_sizes, int n_in,
                              void* d_out, int out_size, void* d_ws, size_t ws_size,
                              hipStream_t stream)
{
    const float* x_sem     = (const float*)d_in[0];
    const float* x_pos     = (const float*)d_in[1];
    const int*   pos_bidx  = (const int*)  d_in[2];
    const float* x_aff     = (const float*)d_in[3];
    const int*   aff_bidx  = (const int*)  d_in[4];
    const int*   edge_type = (const int*)  d_in[5];
    const float* edge_param  = (const float*)d_in[6];
    const float* edge_anchor = (const float*)d_in[7];
    const float* edge_pose   = (const float*)d_in[8];
    const float* sem_W  = (const float*)d_in[10];
    const float* sem_b  = (const float*)d_in[11];
    const float* pos_W1 = (const float*)d_in[12];
    const float* pos_b1 = (const float*)d_in[13];
    const float* pos_bn_g = (const float*)d_in[14];
    const float* pos_bn_b = (const float*)d_in[15];
    const float* pos_W2 = (const float*)d_in[16];
    const float* pos_b2 = (const float*)d_in[17];
    const float* aff_W1 = (const float*)d_in[18];
    const float* aff_b1 = (const float*)d_in[19];
    const float* aff_bn_g = (const float*)d_in[20];
    const float* aff_bn_b = (const float*)d_in[21];
    const float* aff_W2 = (const float*)d_in[22];
    const float* aff_b2 = (const float*)d_in[23];
    const float* nf_W   = (const float*)d_in[24];
    const float* nf_b   = (const float*)d_in[25];
    const float* nf_ln_g = (const float*)d_in[26];
    const float* nf_ln_b = (const float*)d_in[27];
    const float* et_emb = (const float*)d_in[28];
    const float* ep_W1  = (const float*)d_in[29];
    const float* ep_b1  = (const float*)d_in[30];
    const float* ep_ln_g = (const float*)d_in[31];
    const float* ep_ln_b = (const float*)d_in[32];
    const float* ep_W2  = (const float*)d_in[33];
    const float* ep_b2  = (const float*)d_in[34];
    const float* ea_W   = (const float*)d_in[35];
    const float* ea_b   = (const float*)d_in[36];
    const float* epo_W  = (const float*)d_in[37];
    const float* epo_b  = (const float*)d_in[38];
    const float* ef_W   = (const float*)d_in[39];
    const float* ef_b   = (const float*)d_in[40];
    const float* ef_ln_g = (const float*)d_in[41];
    const float* ef_ln_b = (const float*)d_in[42];

    int N  = in_sizes[0] / 512;
    int Pp = in_sizes[1] / 3;
    int Pa = in_sizes[3] / 3;
    int E  = in_sizes[5];
    int N2 = (N + 4095) & ~4095;          // cnt arrays padded for int4 scan

    float* ws = (float*)d_ws;
    size_t off = 0;
    unsigned short* h_pos = (unsigned short*)(ws + off); off += (size_t)N*128;  // bf16
    unsigned short* h_aff = (unsigned short*)(ws + off); off += (size_t)N*128;  // bf16
    float* stats = ws + off;       off += 32;             // [0..15]=pos,[16..31]=aff
    int* cnt_pos = (int*)(ws+off); off += N2;
    int* cnt_aff = (int*)(ws+off); off += N2;
    int* base_pos = (int*)(ws+off); off += N;
    int* base_aff = (int*)(ws+off); off += N;
    off = (off + 3) & ~(size_t)3;                          // 16B align for float4
    float* xs_pos = ws + off;      off += (size_t)Pp*4;
    int* nd_pos = (int*)(ws+off);  off += Pp;
    off = (off + 3) & ~(size_t)3;
    float* xs_aff = ws + off;      off += (size_t)Pa*4;
    int* nd_aff = (int*)(ws+off);  off += Pa;
    off = (off + 3) & ~(size_t)3;
    float* W1f_all = ws + off;     off += 1536;           // pos 768 | aff 768
    float* b1f_all = ws + off;     off += 512;            // pos 256 | aff 256
    float* type_proj  = ws + off;  off += 7*256;
    float* node_const = ws + off;  off += 256;
    float* edge_const = ws + off;  off += 256;
    unsigned short* Wt_all = (unsigned short*)(ws + off);  // pos 64K | aff 64K shorts
    unsigned short* BtN    = Wt_all + 2*65536;
    unsigned short* BtE    = BtN + 256*1024;

    // zero stats + padded CSR counters (contiguous region)
    (void)hipMemsetAsync(stats, 0, (32 + 2*(size_t)N2) * sizeof(int), stream);

    stats_count_kernel<<<1024, 256, 0, stream>>>(x_pos, pos_bidx, Pp,
                                                 x_aff, aff_bidx, Pa,
                                                 stats, cnt_pos, cnt_aff);
    scan2_kernel<<<2, 1024, 0, stream>>>(cnt_pos, cnt_aff, base_pos, base_aff, N);
    scatter_kernel<<<1024, 256, 0, stream>>>(x_pos, pos_bidx, Pp, x_aff, aff_bidx, Pa,
                                             base_pos, base_aff,
                                             (float4*)xs_pos, nd_pos,
                                             (float4*)xs_aff, nd_aff);

    prep_mega<<<1837, 256, 0, stream>>>(sem_W, nf_W, ep_W2, ef_W, ea_W, epo_W, et_emb,
                                        sem_b, nf_b, ep_b2, ea_b, epo_b, ef_b,
                                        stats,
                                        pos_W1, pos_b1, pos_bn_g, pos_bn_b,
                                        aff_W1, aff_b1, aff_bn_g, aff_bn_b,
                                        1.f/(float)Pp, 1.f/(float)Pa,
                                        pos_W2, aff_W2,
                                        BtN, BtE, type_proj,
                                        node_const, edge_const,
                                        W1f_all, b1f_all, Wt_all);

    // after scatter, base_* hold END offsets per node
    int nbPer = (N + 31) / 32;
    pce_seg_kernel<<<2*nbPer*4, 256, 0, stream>>>(xs_pos, nd_pos, base_pos,
                                                  xs_aff, nd_aff, base_aff,
                                                  W1f_all, b1f_all, Wt_all,
                                                  pos_b2, aff_b2,
                                                  h_pos, h_aff, N, nbPer);

    node_mfma_kernel<<<(N + 63)/64, 256, 0, stream>>>(x_sem, h_pos, h_aff, BtN, node_const,
                                                      nf_ln_g, nf_ln_b,
                                                      (float*)d_out, N);
    edge_mfma_kernel<<<(E + 63)/64, 256, 0, stream>>>(edge_type, edge_param, edge_anchor,
                                                      edge_pose, ep_W1, ep_b1,
                                                      ep_ln_g, ep_ln_b, BtE,
                                                      type_proj, edge_const,
                                                      ef_ln_g, ef_ln_b,
                                                      (float*)d_out + (size_t)N*256, E);
}